// Round 1
// baseline (904.076 us; speedup 1.0000x reference)
//
#include <hip/hip_runtime.h>
#include <math.h>

#define BB 16
#define CC 512
#define DD 64
#define NN 4096
#define EPSV 1e-6f

__device__ __forceinline__ float softplus_f(float v) {
    return fmaxf(v, 0.0f) + log1pf(expf(-fabsf(v)));
}

// Build WT[c][j], j in [0,128): j<64 -> Wq[j][c], else Wk[j-64][c]
__global__ __launch_bounds__(256) void k_wt(const float* __restrict__ Wq,
                                            const float* __restrict__ Wk,
                                            float* __restrict__ WT) {
    int i = blockIdx.x * 256 + threadIdx.x;
    if (i < CC * 128) {
        int c = i >> 7, j = i & 127;
        WT[i] = (j < DD) ? Wq[j * CC + c] : Wk[(j - DD) * CC + c];
    }
}

// Q/K projection + bias + softplus. Thread = one pixel.
__global__ __launch_bounds__(128) void k_proj(const float* __restrict__ x,
                                              const float* __restrict__ WT,
                                              const float* __restrict__ bq,
                                              const float* __restrict__ bk,
                                              float* __restrict__ Qo,
                                              float* __restrict__ Ko) {
    int b = blockIdx.y;
    int nn = blockIdx.x * 128 + threadIdx.x;
    const float* xb = x + (size_t)b * CC * NN + nn;
    float q[DD], k[DD];
#pragma unroll
    for (int m = 0; m < DD; ++m) { q[m] = 0.f; k[m] = 0.f; }
    for (int c = 0; c < CC; ++c) {
        float xv = xb[(size_t)c * NN];
        const float* w = WT + c * 128;
#pragma unroll
        for (int m = 0; m < DD; ++m) q[m] = fmaf(w[m], xv, q[m]);
#pragma unroll
        for (int m = 0; m < DD; ++m) k[m] = fmaf(w[DD + m], xv, k[m]);
    }
    float* qp = Qo + ((size_t)b * NN + nn) * DD;
#pragma unroll
    for (int m = 0; m < DD; ++m) qp[m] = softplus_f(q[m] + bq[m]);
#pragma unroll
    for (int m = 0; m < DD; ++m)
        Ko[((size_t)b * DD + m) * NN + nn] = softplus_f(k[m] + bk[m]);
}

// Ksum[b*D+m] = sum_n K[b][m][n]  (raw, no EPS)
__global__ __launch_bounds__(256) void k_ksum(const float* __restrict__ Ko,
                                              float* __restrict__ Ksum) {
    int row = blockIdx.x;
    const float* p = Ko + (size_t)row * NN;
    float s = 0.f;
    for (int i = threadIdx.x; i < NN; i += 256) s += p[i];
    for (int off = 32; off > 0; off >>= 1) s += __shfl_down(s, off, 64);
    __shared__ float red[4];
    if ((threadIdx.x & 63) == 0) red[threadIdx.x >> 6] = s;
    __syncthreads();
    if (threadIdx.x == 0) Ksum[row] = red[0] + red[1] + red[2] + red[3];
}

// KX[b][m][c] += sum_nn K[b][m][nn] * x[b][c][nn]   (split-K over nn, atomics)
__global__ __launch_bounds__(256) void k_kx(const float* __restrict__ Ko,
                                            const float* __restrict__ x,
                                            float* __restrict__ KX) {
    int b = blockIdx.z;
    int chunk = blockIdx.y;       // 8 chunks of 512 pixels
    int c0 = blockIdx.x * 128;
    __shared__ float Kt[64][65];
    __shared__ float Xt[128][65];
    int t = threadIdx.x;
    int mg = (t >> 5) * 8;
    int cg = (t & 31) * 4;
    float acc[8][4];
#pragma unroll
    for (int i = 0; i < 8; ++i)
#pragma unroll
        for (int j = 0; j < 4; ++j) acc[i][j] = 0.f;
    int n0 = chunk * 512;
    for (int step = 0; step < 512; step += 64) {
        int nb = n0 + step;
        for (int i = t; i < 64 * 64; i += 256) {
            int m = i >> 6, nn = i & 63;
            Kt[m][nn] = Ko[((size_t)(b * DD + m)) * NN + nb + nn];
        }
        for (int i = t; i < 128 * 64; i += 256) {
            int c = i >> 6, nn = i & 63;
            Xt[c][nn] = x[((size_t)(b * CC + c0 + c)) * NN + nb + nn];
        }
        __syncthreads();
        for (int nn = 0; nn < 64; ++nn) {
            float kv[8], xv[4];
#pragma unroll
            for (int i = 0; i < 8; ++i) kv[i] = Kt[mg + i][nn];
#pragma unroll
            for (int j = 0; j < 4; ++j) xv[j] = Xt[cg + j][nn];
#pragma unroll
            for (int i = 0; i < 8; ++i)
#pragma unroll
                for (int j = 0; j < 4; ++j) acc[i][j] = fmaf(kv[i], xv[j], acc[i][j]);
        }
        __syncthreads();
    }
#pragma unroll
    for (int i = 0; i < 8; ++i)
#pragma unroll
        for (int j = 0; j < 4; ++j)
            atomicAdd(&KX[((size_t)(b * DD + mg + i)) * CC + c0 + cg + j], acc[i][j]);
}

// KVT[b][c][m] = sum_cp KX[b][m][cp] * Wv[c][cp] + bv[c]*Ksum[b][m]
__global__ __launch_bounds__(256) void k_kv(const float* __restrict__ KX,
                                            const float* __restrict__ Wv,
                                            const float* __restrict__ bv,
                                            const float* __restrict__ Ksum,
                                            float* __restrict__ KVT) {
    int b = blockIdx.y;
    int c0 = blockIdx.x * 64;
    __shared__ float At[64][65];
    __shared__ float Bt[64][65];
    int t = threadIdx.x;
    int mg = (t >> 4) * 4;
    int cg = (t & 15) * 4;
    float acc[4][4];
#pragma unroll
    for (int i = 0; i < 4; ++i)
#pragma unroll
        for (int j = 0; j < 4; ++j) acc[i][j] = 0.f;
    for (int cp0 = 0; cp0 < CC; cp0 += 64) {
        for (int i = t; i < 64 * 64; i += 256) {
            int r = i >> 6, cp = i & 63;
            At[r][cp] = KX[((size_t)(b * DD + r)) * CC + cp0 + cp];
            Bt[r][cp] = Wv[((size_t)(c0 + r)) * CC + cp0 + cp];
        }
        __syncthreads();
        for (int cp = 0; cp < 64; ++cp) {
            float a[4], w[4];
#pragma unroll
            for (int i = 0; i < 4; ++i) a[i] = At[mg + i][cp];
#pragma unroll
            for (int j = 0; j < 4; ++j) w[j] = Bt[cg + j][cp];
#pragma unroll
            for (int i = 0; i < 4; ++i)
#pragma unroll
                for (int j = 0; j < 4; ++j) acc[i][j] = fmaf(a[i], w[j], acc[i][j]);
        }
        __syncthreads();
    }
#pragma unroll
    for (int i = 0; i < 4; ++i)
#pragma unroll
        for (int j = 0; j < 4; ++j) {
            int m = mg + i, c = c0 + cg + j;
            KVT[((size_t)b * CC + c) * DD + m] = acc[i][j] + bv[c] * Ksum[b * DD + m];
        }
}

// out[b][c][nn] = x + gamma * norm(nn) * sum_m Q[nn][m]*KVT[c][m]
__global__ __launch_bounds__(128) void k_out(const float* __restrict__ x,
                                             const float* __restrict__ Qo,
                                             const float* __restrict__ KVT,
                                             const float* __restrict__ Ksum,
                                             const float* __restrict__ gamma,
                                             float* __restrict__ out) {
    int b = blockIdx.y;
    int nn = blockIdx.x * 128 + threadIdx.x;
    const float* qp = Qo + ((size_t)b * NN + nn) * DD;
    float q[DD];
#pragma unroll
    for (int m = 0; m < DD; ++m) q[m] = qp[m];
    float dot = 0.f;
#pragma unroll
    for (int m = 0; m < DD; ++m) dot = fmaf(q[m], Ksum[b * DD + m] + EPSV, dot);
    float scale = gamma[0] / dot;
    const float* kvb = KVT + (size_t)b * CC * DD;
    const float* xb = x + (size_t)b * CC * NN + nn;
    float* ob = out + (size_t)b * CC * NN + nn;
    for (int c = 0; c < CC; ++c) {
        const float* kr = kvb + c * DD;
        float acc = 0.f;
#pragma unroll
        for (int m = 0; m < DD; ++m) acc = fmaf(q[m], kr[m], acc);
        ob[(size_t)c * NN] = xb[(size_t)c * NN] + scale * acc;
    }
}

extern "C" void kernel_launch(void* const* d_in, const int* in_sizes, int n_in,
                              void* d_out, int out_size, void* d_ws, size_t ws_size,
                              hipStream_t stream) {
    const float* x     = (const float*)d_in[0];
    const float* Wq    = (const float*)d_in[1];
    const float* bq    = (const float*)d_in[2];
    const float* Wk    = (const float*)d_in[3];
    const float* bk    = (const float*)d_in[4];
    const float* Wv    = (const float*)d_in[5];
    const float* bv    = (const float*)d_in[6];
    const float* gamma = (const float*)d_in[7];
    float* out = (float*)d_out;

    float* ws   = (float*)d_ws;
    float* Ko   = ws;                          // B*D*N = 4,194,304 floats
    float* Qo   = Ko + (size_t)BB * DD * NN;   // B*N*D = 4,194,304
    float* KX   = Qo + (size_t)BB * NN * DD;   // B*D*C = 524,288
    float* Ksum = KX + (size_t)BB * DD * CC;   // B*D   = 1,024
    float* KVT  = Ksum + BB * DD;              // B*C*D = 524,288
    float* WT   = KVT + (size_t)BB * CC * DD;  // C*128 = 65,536

    hipMemsetAsync(KX, 0, (size_t)BB * DD * CC * sizeof(float), stream);
    k_wt<<<dim3(256), dim3(256), 0, stream>>>(Wq, Wk, WT);
    k_proj<<<dim3(NN / 128, BB), dim3(128), 0, stream>>>(x, WT, bq, bk, Qo, Ko);
    k_ksum<<<dim3(BB * DD), dim3(256), 0, stream>>>(Ko, Ksum);
    k_kx<<<dim3(CC / 128, 8, BB), dim3(256), 0, stream>>>(Ko, x, KX);
    k_kv<<<dim3(CC / 64, BB), dim3(256), 0, stream>>>(KX, Wv, bv, Ksum, KVT);
    k_out<<<dim3(NN / 128, BB), dim3(128), 0, stream>>>(x, Qo, KVT, Ksum, gamma, out);
}

// Round 2
// 392.440 us; speedup vs baseline: 2.3037x; 2.3037x over previous
//
#include <hip/hip_runtime.h>
#include <hip/hip_bf16.h>
#include <math.h>

#define BB 16
#define CC 512
#define DD 64
#define NN 4096
#define EPSV 1e-6f

typedef __attribute__((ext_vector_type(8))) short short8;
typedef __attribute__((ext_vector_type(4))) float f32x4;

__device__ __forceinline__ float softplus_f(float v) {
    return fmaxf(v, 0.0f) + log1pf(expf(-fabsf(v)));
}

// ---- prep: Wcat bf16 [128][512]  (rows 0-63 = Wq, 64-127 = Wk) ----
__global__ __launch_bounds__(256) void k_wcast(const float* __restrict__ Wq,
                                               const float* __restrict__ Wk,
                                               __hip_bfloat16* __restrict__ Wcat) {
    int i = blockIdx.x * 256 + threadIdx.x;
    if (i < 128 * CC) {
        int j = i >> 9, c = i & 511;
        float v = (j < DD) ? Wq[j * CC + c] : Wk[(j - DD) * CC + c];
        Wcat[i] = __float2bfloat16(v);
    }
}

// ---- prep: xt[b][n][c] bf16 (transpose of x) ----
__global__ __launch_bounds__(256) void k_xt(const float* __restrict__ x,
                                            __hip_bfloat16* __restrict__ xt) {
    int b = blockIdx.z;
    int n0 = blockIdx.x * 64, c0 = blockIdx.y * 64;
    __shared__ float tile[64][65];
    const float* xb = x + ((size_t)b * CC + c0) * NN + n0;
    int t = threadIdx.x;
#pragma unroll
    for (int i = 0; i < 16; ++i) {
        int idx = i * 256 + t;
        int c = idx >> 6, n = idx & 63;
        tile[c][n] = xb[(size_t)c * NN + n];
    }
    __syncthreads();
    __hip_bfloat16* xo = xt + ((size_t)b * NN + n0) * CC + c0;
#pragma unroll
    for (int i = 0; i < 16; ++i) {
        int idx = i * 256 + t;
        int n = idx >> 6, c = idx & 63;
        xo[(size_t)n * CC + c] = __float2bfloat16(tile[c][n]);
    }
}

// ---- Q/K projection via MFMA.  Qb[b][n][d] bf16 ; Ko[b][m][n] fp32 ----
__global__ __launch_bounds__(256) void k_proj(const __hip_bfloat16* __restrict__ xt,
                                              const __hip_bfloat16* __restrict__ Wcat,
                                              const float* __restrict__ bq,
                                              const float* __restrict__ bk,
                                              __hip_bfloat16* __restrict__ Qb,
                                              float* __restrict__ Ko) {
    int b = blockIdx.y;
    int n_blk = blockIdx.x * 128;
    int wave = threadIdx.x >> 6;
    int lane = threadIdx.x & 63;
    int n_wave = n_blk + wave * 32;           // wave owns 32 n-rows
    int l16 = lane & 15, g = lane >> 4;

    f32x4 accQ[2][4] = {};                    // D[n][j], j in [0,64)
    f32x4 accK[4][2] = {};                    // D[j][n], j in [64,128)

    const short8* xtp = reinterpret_cast<const short8*>(xt) + ((size_t)b * NN + n_wave) * 64;
    const short8* wp  = reinterpret_cast<const short8*>(Wcat);

    for (int ck = 0; ck < 16; ++ck) {         // 512 c in steps of 32
        int ch = ck * 4 + g;                  // 8-elem chunk index
        short8 xf[2], wf[8];
#pragma unroll
        for (int nf = 0; nf < 2; ++nf) xf[nf] = xtp[(size_t)(nf * 16 + l16) * 64 + ch];
#pragma unroll
        for (int jf = 0; jf < 8; ++jf) wf[jf] = wp[(size_t)(jf * 16 + l16) * 64 + ch];
#pragma unroll
        for (int nf = 0; nf < 2; ++nf)
#pragma unroll
            for (int jf = 0; jf < 4; ++jf)
                accQ[nf][jf] = __builtin_amdgcn_mfma_f32_16x16x32_bf16(xf[nf], wf[jf], accQ[nf][jf], 0, 0, 0);
#pragma unroll
        for (int jf = 0; jf < 4; ++jf)
#pragma unroll
            for (int nf = 0; nf < 2; ++nf)
                accK[jf][nf] = __builtin_amdgcn_mfma_f32_16x16x32_bf16(wf[4 + jf], xf[nf], accK[jf][nf], 0, 0, 0);
    }
    // Q epilogue: row n = n_wave + nf*16 + 4g + r, col j = jf*16 + l16
#pragma unroll
    for (int nf = 0; nf < 2; ++nf)
#pragma unroll
        for (int jf = 0; jf < 4; ++jf)
#pragma unroll
            for (int r = 0; r < 4; ++r) {
                int n = n_wave + nf * 16 + 4 * g + r;
                int j = jf * 16 + l16;
                float v = softplus_f(accQ[nf][jf][r] + bq[j]);
                Qb[((size_t)b * NN + n) * DD + j] = __float2bfloat16(v);
            }
    // K epilogue: row m = jf*16 + 4g + r, col n = n_wave + nf*16 + l16
#pragma unroll
    for (int jf = 0; jf < 4; ++jf)
#pragma unroll
        for (int nf = 0; nf < 2; ++nf)
#pragma unroll
            for (int r = 0; r < 4; ++r) {
                int m = jf * 16 + 4 * g + r;
                int n = n_wave + nf * 16 + l16;
                float v = softplus_f(accK[jf][nf][r] + bk[m]);
                Ko[((size_t)b * DD + m) * NN + n] = v;
            }
}

// ---- Ksum[b*D+m] = sum_n K[b][m][n]  (raw) ----
__global__ __launch_bounds__(256) void k_ksum(const float* __restrict__ Ko,
                                              float* __restrict__ Ksum) {
    int row = blockIdx.x;
    const float* p = Ko + (size_t)row * NN;
    float s = 0.f;
    for (int i = threadIdx.x; i < NN; i += 256) s += p[i];
    for (int off = 32; off > 0; off >>= 1) s += __shfl_down(s, off, 64);
    __shared__ float red[4];
    if ((threadIdx.x & 63) == 0) red[threadIdx.x >> 6] = s;
    __syncthreads();
    if (threadIdx.x == 0) Ksum[row] = red[0] + red[1] + red[2] + red[3];
}

// ---- KX[b][m][c] += sum_nn K[m][nn]*x[c][nn]  (unchanged VALU split-K) ----
__global__ __launch_bounds__(256) void k_kx(const float* __restrict__ Ko,
                                            const float* __restrict__ x,
                                            float* __restrict__ KX) {
    int b = blockIdx.z;
    int chunk = blockIdx.y;
    int c0 = blockIdx.x * 128;
    __shared__ float Kt[64][65];
    __shared__ float Xt[128][65];
    int t = threadIdx.x;
    int mg = (t >> 5) * 8;
    int cg = (t & 31) * 4;
    float acc[8][4];
#pragma unroll
    for (int i = 0; i < 8; ++i)
#pragma unroll
        for (int j = 0; j < 4; ++j) acc[i][j] = 0.f;
    int n0 = chunk * 512;
    for (int step = 0; step < 512; step += 64) {
        int nb = n0 + step;
        for (int i = t; i < 64 * 64; i += 256) {
            int m = i >> 6, nn = i & 63;
            Kt[m][nn] = Ko[((size_t)(b * DD + m)) * NN + nb + nn];
        }
        for (int i = t; i < 128 * 64; i += 256) {
            int c = i >> 6, nn = i & 63;
            Xt[c][nn] = x[((size_t)(b * CC + c0 + c)) * NN + nb + nn];
        }
        __syncthreads();
        for (int nn = 0; nn < 64; ++nn) {
            float kv[8], xv[4];
#pragma unroll
            for (int i = 0; i < 8; ++i) kv[i] = Kt[mg + i][nn];
#pragma unroll
            for (int j = 0; j < 4; ++j) xv[j] = Xt[cg + j][nn];
#pragma unroll
            for (int i = 0; i < 8; ++i)
#pragma unroll
                for (int j = 0; j < 4; ++j) acc[i][j] = fmaf(kv[i], xv[j], acc[i][j]);
        }
        __syncthreads();
    }
#pragma unroll
    for (int i = 0; i < 8; ++i)
#pragma unroll
        for (int j = 0; j < 4; ++j)
            atomicAdd(&KX[((size_t)(b * DD + mg + i)) * CC + c0 + cg + j], acc[i][j]);
}

// ---- KVTb[b][c][m] bf16 = sum_cp KX[b][m][cp]*Wv[c][cp] + bv[c]*Ksum[b][m] ----
__global__ __launch_bounds__(256) void k_kv(const float* __restrict__ KX,
                                            const float* __restrict__ Wv,
                                            const float* __restrict__ bv,
                                            const float* __restrict__ Ksum,
                                            __hip_bfloat16* __restrict__ KVTb) {
    int b = blockIdx.y;
    int c0 = blockIdx.x * 64;
    __shared__ float At[64][65];
    __shared__ float Bt[64][65];
    int t = threadIdx.x;
    int mg = (t >> 4) * 4;
    int cg = (t & 15) * 4;
    float acc[4][4];
#pragma unroll
    for (int i = 0; i < 4; ++i)
#pragma unroll
        for (int j = 0; j < 4; ++j) acc[i][j] = 0.f;
    for (int cp0 = 0; cp0 < CC; cp0 += 64) {
        for (int i = t; i < 64 * 64; i += 256) {
            int r = i >> 6, cp = i & 63;
            At[r][cp] = KX[((size_t)(b * DD + r)) * CC + cp0 + cp];
            Bt[r][cp] = Wv[((size_t)(c0 + r)) * CC + cp0 + cp];
        }
        __syncthreads();
        for (int cp = 0; cp < 64; ++cp) {
            float a[4], w[4];
#pragma unroll
            for (int i = 0; i < 4; ++i) a[i] = At[mg + i][cp];
#pragma unroll
            for (int j = 0; j < 4; ++j) w[j] = Bt[cg + j][cp];
#pragma unroll
            for (int i = 0; i < 4; ++i)
#pragma unroll
                for (int j = 0; j < 4; ++j) acc[i][j] = fmaf(a[i], w[j], acc[i][j]);
        }
        __syncthreads();
    }
#pragma unroll
    for (int i = 0; i < 4; ++i)
#pragma unroll
        for (int j = 0; j < 4; ++j) {
            int m = mg + i, c = c0 + cg + j;
            KVTb[((size_t)b * CC + c) * DD + m] =
                __float2bfloat16(acc[i][j] + bv[c] * Ksum[b * DD + m]);
        }
}

// ---- normv[b*N+n] = gamma / sum_m Q[n][m]*(Ksum[m]+eps) ----
__global__ __launch_bounds__(256) void k_norm(const __hip_bfloat16* __restrict__ Qb,
                                              const float* __restrict__ Ksum,
                                              const float* __restrict__ gamma,
                                              float* __restrict__ normv) {
    int i = blockIdx.x * 256 + threadIdx.x;   // i = b*N + n
    int b = i >> 12;
    const __hip_bfloat16* q = Qb + (size_t)i * DD;
    const float* ks = Ksum + b * DD;
    float dot = 0.f;
#pragma unroll
    for (int m = 0; m < DD; ++m) dot = fmaf(__bfloat162float(q[m]), ks[m] + EPSV, dot);
    normv[i] = gamma[0] / dot;
}

// ---- out[c][n] = x + normv[n] * sum_m KVT[c][m]*Q[n][m]   (MFMA, K=64) ----
__global__ __launch_bounds__(256) void k_out(const float* __restrict__ x,
                                             const __hip_bfloat16* __restrict__ Qb,
                                             const __hip_bfloat16* __restrict__ KVTb,
                                             const float* __restrict__ normv,
                                             float* __restrict__ out) {
    int b = blockIdx.z;
    int c_blk = blockIdx.x * 128, n_blk = blockIdx.y * 128;
    int wave = threadIdx.x >> 6, lane = threadIdx.x & 63;
    int cw = c_blk + (wave >> 1) * 64, nw = n_blk + (wave & 1) * 64;
    int l16 = lane & 15, g = lane >> 4;

    f32x4 acc[4][4] = {};
    const short8* ap = reinterpret_cast<const short8*>(KVTb) + ((size_t)b * CC + cw) * 8;
    const short8* bp = reinterpret_cast<const short8*>(Qb) + ((size_t)b * NN + nw) * 8;
#pragma unroll
    for (int ck = 0; ck < 2; ++ck) {
        int ch = ck * 4 + g;
        short8 af[4], bf[4];
#pragma unroll
        for (int i = 0; i < 4; ++i) af[i] = ap[(size_t)(i * 16 + l16) * 8 + ch];
#pragma unroll
        for (int i = 0; i < 4; ++i) bf[i] = bp[(size_t)(i * 16 + l16) * 8 + ch];
#pragma unroll
        for (int i = 0; i < 4; ++i)
#pragma unroll
            for (int j = 0; j < 4; ++j)
                acc[i][j] = __builtin_amdgcn_mfma_f32_16x16x32_bf16(af[i], bf[j], acc[i][j], 0, 0, 0);
    }
    float sc[4];
#pragma unroll
    for (int j = 0; j < 4; ++j) sc[j] = normv[(size_t)b * NN + nw + j * 16 + l16];
    const float* xb = x + (size_t)b * CC * NN;
    float* ob = out + (size_t)b * CC * NN;
#pragma unroll
    for (int i = 0; i < 4; ++i)
#pragma unroll
        for (int r = 0; r < 4; ++r) {
            int c = cw + i * 16 + 4 * g + r;
            size_t rowoff = (size_t)c * NN;
#pragma unroll
            for (int j = 0; j < 4; ++j) {
                int n = nw + j * 16 + l16;
                ob[rowoff + n] = xb[rowoff + n] + sc[j] * acc[i][j][r];
            }
        }
}

extern "C" void kernel_launch(void* const* d_in, const int* in_sizes, int n_in,
                              void* d_out, int out_size, void* d_ws, size_t ws_size,
                              hipStream_t stream) {
    const float* x     = (const float*)d_in[0];
    const float* Wq    = (const float*)d_in[1];
    const float* bq    = (const float*)d_in[2];
    const float* Wk    = (const float*)d_in[3];
    const float* bk    = (const float*)d_in[4];
    const float* Wv    = (const float*)d_in[5];
    const float* bv    = (const float*)d_in[6];
    const float* gamma = (const float*)d_in[7];
    float* out = (float*)d_out;

    float* ws    = (float*)d_ws;
    float* Ko    = ws;                                   // B*D*N fp32
    float* KX    = Ko + (size_t)BB * DD * NN;            // B*D*C fp32
    float* Ksum  = KX + (size_t)BB * DD * CC;            // B*D fp32
    float* normv = Ksum + BB * DD;                       // B*N fp32
    __hip_bfloat16* Qb   = (__hip_bfloat16*)(normv + (size_t)BB * NN);  // B*N*D bf16
    __hip_bfloat16* KVTb = Qb + (size_t)BB * NN * DD;    // B*C*D bf16
    __hip_bfloat16* Wcat = KVTb + (size_t)BB * CC * DD;  // 128*C bf16
    __hip_bfloat16* xt   = Wcat + 128 * CC;              // B*N*C bf16

    hipMemsetAsync(KX, 0, (size_t)BB * DD * CC * sizeof(float), stream);
    k_wcast<<<dim3(128 * CC / 256), dim3(256), 0, stream>>>(Wq, Wk, Wcat);
    k_xt<<<dim3(NN / 64, CC / 64, BB), dim3(256), 0, stream>>>(x, xt);
    k_proj<<<dim3(NN / 128, BB), dim3(256), 0, stream>>>(xt, Wcat, bq, bk, Qb, Ko);
    k_ksum<<<dim3(BB * DD), dim3(256), 0, stream>>>(Ko, Ksum);
    k_kx<<<dim3(CC / 128, 8, BB), dim3(256), 0, stream>>>(Ko, x, KX);
    k_kv<<<dim3(CC / 64, BB), dim3(256), 0, stream>>>(KX, Wv, bv, Ksum, KVTb);
    k_norm<<<dim3(BB * NN / 256), dim3(256), 0, stream>>>(Qb, Ksum, gamma, normv);
    k_out<<<dim3(CC / 128, NN / 128, BB), dim3(256), 0, stream>>>(x, Qb, KVTb, normv, out);
}

// Round 3
// 289.792 us; speedup vs baseline: 3.1197x; 1.3542x over previous
//
#include <hip/hip_runtime.h>
#include <hip/hip_bf16.h>
#include <math.h>

#define BB 16
#define CC 512
#define DD 64
#define NN 4096
#define EPSV 1e-6f

typedef __attribute__((ext_vector_type(8))) short short8;
typedef __attribute__((ext_vector_type(4))) float f32x4;

__device__ __forceinline__ float softplus_f(float v) {
    return fmaxf(v, 0.0f) + log1pf(expf(-fabsf(v)));
}
__device__ __forceinline__ short bf16s(float f) {
    __hip_bfloat16 h = __float2bfloat16(f);
    return __builtin_bit_cast(short, h);
}
__device__ __forceinline__ float sbf16(short s) {
    return __bfloat162float(__builtin_bit_cast(__hip_bfloat16, s));
}

// ---- prep: Wcat bf16 [128][512]  (rows 0-63 = Wq, 64-127 = Wk) ----
__global__ __launch_bounds__(256) void k_wcast(const float* __restrict__ Wq,
                                               const float* __restrict__ Wk,
                                               __hip_bfloat16* __restrict__ Wcat) {
    int i = blockIdx.x * 256 + threadIdx.x;
    if (i < 128 * CC) {
        int j = i >> 9, c = i & 511;
        float v = (j < DD) ? Wq[j * CC + c] : Wk[(j - DD) * CC + c];
        Wcat[i] = __float2bfloat16(v);
    }
}

// ---- prep: xt[b][n][c] bf16 (transpose of x) ----
__global__ __launch_bounds__(256) void k_xt(const float* __restrict__ x,
                                            __hip_bfloat16* __restrict__ xt) {
    int b = blockIdx.z;
    int n0 = blockIdx.x * 64, c0 = blockIdx.y * 64;
    __shared__ float tile[64][65];
    const float* xb = x + ((size_t)b * CC + c0) * NN + n0;
    int t = threadIdx.x;
#pragma unroll
    for (int i = 0; i < 16; ++i) {
        int idx = i * 256 + t;
        int c = idx >> 6, n = idx & 63;
        tile[c][n] = xb[(size_t)c * NN + n];
    }
    __syncthreads();
    __hip_bfloat16* xo = xt + ((size_t)b * NN + n0) * CC + c0;
#pragma unroll
    for (int i = 0; i < 16; ++i) {
        int idx = i * 256 + t;
        int n = idx >> 6, c = idx & 63;
        xo[(size_t)n * CC + c] = __float2bfloat16(tile[c][n]);
    }
}

// ---- Q/K projection via MFMA.  Qb[b][n][d] bf16 ; Kb[b][m][n] bf16 ----
__global__ __launch_bounds__(256) void k_proj(const __hip_bfloat16* __restrict__ xt,
                                              const __hip_bfloat16* __restrict__ Wcat,
                                              const float* __restrict__ bq,
                                              const float* __restrict__ bk,
                                              __hip_bfloat16* __restrict__ Qb,
                                              __hip_bfloat16* __restrict__ Kb) {
    int b = blockIdx.y;
    int n_blk = blockIdx.x * 128;
    int wave = threadIdx.x >> 6;
    int lane = threadIdx.x & 63;
    int n_wave = n_blk + wave * 32;           // wave owns 32 n-rows
    int l16 = lane & 15, g = lane >> 4;

    f32x4 accQ[2][4] = {};                    // D[n][j], j in [0,64)
    f32x4 accK[4][2] = {};                    // D[j][n], j in [64,128)

    const short8* xtp = reinterpret_cast<const short8*>(xt) + ((size_t)b * NN + n_wave) * 64;
    const short8* wp  = reinterpret_cast<const short8*>(Wcat);

    for (int ck = 0; ck < 16; ++ck) {         // 512 c in steps of 32
        int ch = ck * 4 + g;                  // 8-elem chunk index
        short8 xf[2], wf[8];
#pragma unroll
        for (int nf = 0; nf < 2; ++nf) xf[nf] = xtp[(size_t)(nf * 16 + l16) * 64 + ch];
#pragma unroll
        for (int jf = 0; jf < 8; ++jf) wf[jf] = wp[(size_t)(jf * 16 + l16) * 64 + ch];
#pragma unroll
        for (int nf = 0; nf < 2; ++nf)
#pragma unroll
            for (int jf = 0; jf < 4; ++jf)
                accQ[nf][jf] = __builtin_amdgcn_mfma_f32_16x16x32_bf16(xf[nf], wf[jf], accQ[nf][jf], 0, 0, 0);
#pragma unroll
        for (int jf = 0; jf < 4; ++jf)
#pragma unroll
            for (int nf = 0; nf < 2; ++nf)
                accK[jf][nf] = __builtin_amdgcn_mfma_f32_16x16x32_bf16(wf[4 + jf], xf[nf], accK[jf][nf], 0, 0, 0);
    }
    // Q epilogue: row n = n_wave + nf*16 + 4g + r, col j = jf*16 + l16
#pragma unroll
    for (int nf = 0; nf < 2; ++nf)
#pragma unroll
        for (int jf = 0; jf < 4; ++jf)
#pragma unroll
            for (int r = 0; r < 4; ++r) {
                int n = n_wave + nf * 16 + 4 * g + r;
                int j = jf * 16 + l16;
                float v = softplus_f(accQ[nf][jf][r] + bq[j]);
                Qb[((size_t)b * NN + n) * DD + j] = __float2bfloat16(v);
            }
    // K epilogue: row m = jf*16 + 4g + r, col n = n_wave + nf*16 + l16
#pragma unroll
    for (int jf = 0; jf < 4; ++jf)
#pragma unroll
        for (int nf = 0; nf < 2; ++nf)
#pragma unroll
            for (int r = 0; r < 4; ++r) {
                int m = jf * 16 + 4 * g + r;
                int n = n_wave + nf * 16 + l16;
                float v = softplus_f(accK[jf][nf][r] + bk[m]);
                Kb[((size_t)b * DD + m) * NN + n] = __float2bfloat16(v);
            }
}

// ---- Ksum[b*D+m] = sum_n K[b][m][n]  (raw, fp32 accumulate of bf16) ----
__global__ __launch_bounds__(256) void k_ksum(const __hip_bfloat16* __restrict__ Kb,
                                              float* __restrict__ Ksum) {
    int row = blockIdx.x;
    const short8* p = reinterpret_cast<const short8*>(Kb + (size_t)row * NN);
    float s = 0.f;
    for (int i = threadIdx.x; i < NN / 8; i += 256) {
        short8 v = p[i];
#pragma unroll
        for (int e = 0; e < 8; ++e) s += sbf16(v[e]);
    }
    for (int off = 32; off > 0; off >>= 1) s += __shfl_down(s, off, 64);
    __shared__ float red[4];
    if ((threadIdx.x & 63) == 0) red[threadIdx.x >> 6] = s;
    __syncthreads();
    if (threadIdx.x == 0) Ksum[row] = red[0] + red[1] + red[2] + red[3];
}

// ---- KX[b][m][c] += sum_nn Kb[m][nn]*x[c][nn]  (MFMA, no LDS, split-K atomics) ----
__global__ __launch_bounds__(256) void k_kx(const __hip_bfloat16* __restrict__ Kb,
                                            const float* __restrict__ x,
                                            float* __restrict__ KX) {
    int b = blockIdx.z;
    int n0 = blockIdx.y * 256;                // 16 n-chunks
    int c0 = blockIdx.x * 256;                // 2 c-halves
    int wave = threadIdx.x >> 6, lane = threadIdx.x & 63;
    int cw = c0 + wave * 64;                  // wave owns 64 c-cols
    int l16 = lane & 15, g = lane >> 4;

    f32x4 acc[4][4] = {};                     // [mi][cj]
    const __hip_bfloat16* kp = Kb + (size_t)b * DD * NN;
    const float* xp = x + (size_t)b * CC * NN;

#pragma unroll
    for (int ks = 0; ks < 8; ++ks) {          // 256 n in steps of 32
        int nk = n0 + ks * 32 + g * 8;
        short8 af[4];
#pragma unroll
        for (int mi = 0; mi < 4; ++mi)
            af[mi] = *reinterpret_cast<const short8*>(kp + (size_t)(mi * 16 + l16) * NN + nk);
        short8 bf[4];
#pragma unroll
        for (int cj = 0; cj < 4; ++cj) {
            const float* xr = xp + (size_t)(cw + cj * 16 + l16) * NN + nk;
            f32x4 lo = *reinterpret_cast<const f32x4*>(xr);
            f32x4 hi = *reinterpret_cast<const f32x4*>(xr + 4);
            short8 v;
#pragma unroll
            for (int e = 0; e < 4; ++e) { v[e] = bf16s(lo[e]); v[4 + e] = bf16s(hi[e]); }
            bf[cj] = v;
        }
#pragma unroll
        for (int mi = 0; mi < 4; ++mi)
#pragma unroll
            for (int cj = 0; cj < 4; ++cj)
                acc[mi][cj] = __builtin_amdgcn_mfma_f32_16x16x32_bf16(af[mi], bf[cj], acc[mi][cj], 0, 0, 0);
    }
    // D: row m = mi*16 + 4g + r, col c = cw + cj*16 + l16
#pragma unroll
    for (int mi = 0; mi < 4; ++mi)
#pragma unroll
        for (int cj = 0; cj < 4; ++cj)
#pragma unroll
            for (int r = 0; r < 4; ++r) {
                int m = mi * 16 + 4 * g + r;
                int c = cw + cj * 16 + l16;
                atomicAdd(&KX[((size_t)(b * DD + m)) * CC + c], acc[mi][cj][r]);
            }
}

// ---- KVTb[b][c][m] bf16 = sum_cp KX[b][m][cp]*Wv[c][cp] + bv[c]*Ksum[b][m] ----
__global__ __launch_bounds__(256) void k_kv(const float* __restrict__ KX,
                                            const float* __restrict__ Wv,
                                            const float* __restrict__ bv,
                                            const float* __restrict__ Ksum,
                                            __hip_bfloat16* __restrict__ KVTb) {
    int b = blockIdx.y;
    int c0 = blockIdx.x * 64;
    __shared__ float At[64][65];
    __shared__ float Bt[64][65];
    int t = threadIdx.x;
    int mg = (t >> 4) * 4;
    int cg = (t & 15) * 4;
    float acc[4][4];
#pragma unroll
    for (int i = 0; i < 4; ++i)
#pragma unroll
        for (int j = 0; j < 4; ++j) acc[i][j] = 0.f;
    for (int cp0 = 0; cp0 < CC; cp0 += 64) {
        for (int i = t; i < 64 * 64; i += 256) {
            int r = i >> 6, cp = i & 63;
            At[r][cp] = KX[((size_t)(b * DD + r)) * CC + cp0 + cp];
            Bt[r][cp] = Wv[((size_t)(c0 + r)) * CC + cp0 + cp];
        }
        __syncthreads();
        for (int cp = 0; cp < 64; ++cp) {
            float a[4], w[4];
#pragma unroll
            for (int i = 0; i < 4; ++i) a[i] = At[mg + i][cp];
#pragma unroll
            for (int j = 0; j < 4; ++j) w[j] = Bt[cg + j][cp];
#pragma unroll
            for (int i = 0; i < 4; ++i)
#pragma unroll
                for (int j = 0; j < 4; ++j) acc[i][j] = fmaf(a[i], w[j], acc[i][j]);
        }
        __syncthreads();
    }
#pragma unroll
    for (int i = 0; i < 4; ++i)
#pragma unroll
        for (int j = 0; j < 4; ++j) {
            int m = mg + i, c = c0 + cg + j;
            KVTb[((size_t)b * CC + c) * DD + m] =
                __float2bfloat16(acc[i][j] + bv[c] * Ksum[b * DD + m]);
        }
}

// ---- normv[b*N+n] = gamma / sum_m Q[n][m]*(Ksum[m]+eps) ----
__global__ __launch_bounds__(256) void k_norm(const __hip_bfloat16* __restrict__ Qb,
                                              const float* __restrict__ Ksum,
                                              const float* __restrict__ gamma,
                                              float* __restrict__ normv) {
    int i = blockIdx.x * 256 + threadIdx.x;   // i = b*N + n
    int b = i >> 12;
    const short8* q = reinterpret_cast<const short8*>(Qb + (size_t)i * DD);
    const float* ks = Ksum + b * DD;
    float dot = 0.f;
#pragma unroll
    for (int v8 = 0; v8 < 8; ++v8) {
        short8 v = q[v8];
#pragma unroll
        for (int e = 0; e < 8; ++e) dot = fmaf(sbf16(v[e]), ks[v8 * 8 + e] + EPSV, dot);
    }
    normv[i] = gamma[0] / dot;
}

// ---- out[c][n] = x + normv[n] * sum_m KVT[c][m]*Q[n][m]   (MFMA, K=64) ----
__global__ __launch_bounds__(256) void k_out(const float* __restrict__ x,
                                             const __hip_bfloat16* __restrict__ Qb,
                                             const __hip_bfloat16* __restrict__ KVTb,
                                             const float* __restrict__ normv,
                                             float* __restrict__ out) {
    int b = blockIdx.z;
    int c_blk = blockIdx.x * 128, n_blk = blockIdx.y * 128;
    int wave = threadIdx.x >> 6, lane = threadIdx.x & 63;
    int cw = c_blk + (wave >> 1) * 64, nw = n_blk + (wave & 1) * 64;
    int l16 = lane & 15, g = lane >> 4;

    f32x4 acc[4][4] = {};
    const short8* ap = reinterpret_cast<const short8*>(KVTb) + ((size_t)b * CC + cw) * 8;
    const short8* bp = reinterpret_cast<const short8*>(Qb) + ((size_t)b * NN + nw) * 8;
#pragma unroll
    for (int ck = 0; ck < 2; ++ck) {
        int ch = ck * 4 + g;
        short8 af[4], bf[4];
#pragma unroll
        for (int i = 0; i < 4; ++i) af[i] = ap[(size_t)(i * 16 + l16) * 8 + ch];
#pragma unroll
        for (int i = 0; i < 4; ++i) bf[i] = bp[(size_t)(i * 16 + l16) * 8 + ch];
#pragma unroll
        for (int i = 0; i < 4; ++i)
#pragma unroll
            for (int j = 0; j < 4; ++j)
                acc[i][j] = __builtin_amdgcn_mfma_f32_16x16x32_bf16(af[i], bf[j], acc[i][j], 0, 0, 0);
    }
    float sc[4];
#pragma unroll
    for (int j = 0; j < 4; ++j) sc[j] = normv[(size_t)b * NN + nw + j * 16 + l16];
    const float* xb = x + (size_t)b * CC * NN;
    float* ob = out + (size_t)b * CC * NN;
#pragma unroll
    for (int i = 0; i < 4; ++i)
#pragma unroll
        for (int r = 0; r < 4; ++r) {
            int c = cw + i * 16 + 4 * g + r;
            size_t rowoff = (size_t)c * NN;
#pragma unroll
            for (int j = 0; j < 4; ++j) {
                int n = nw + j * 16 + l16;
                ob[rowoff + n] = xb[rowoff + n] + sc[j] * acc[i][j][r];
            }
        }
}

extern "C" void kernel_launch(void* const* d_in, const int* in_sizes, int n_in,
                              void* d_out, int out_size, void* d_ws, size_t ws_size,
                              hipStream_t stream) {
    const float* x     = (const float*)d_in[0];
    const float* Wq    = (const float*)d_in[1];
    const float* bq    = (const float*)d_in[2];
    const float* Wk    = (const float*)d_in[3];
    const float* bk    = (const float*)d_in[4];
    const float* Wv    = (const float*)d_in[5];
    const float* bv    = (const float*)d_in[6];
    const float* gamma = (const float*)d_in[7];
    float* out = (float*)d_out;

    float* ws    = (float*)d_ws;
    float* KX    = ws;                                   // B*D*C fp32
    float* Ksum  = KX + (size_t)BB * DD * CC;            // B*D fp32
    float* normv = Ksum + BB * DD;                       // B*N fp32
    __hip_bfloat16* Qb   = (__hip_bfloat16*)(normv + (size_t)BB * NN);  // B*N*D bf16
    __hip_bfloat16* Kb   = Qb + (size_t)BB * NN * DD;    // B*D*N bf16
    __hip_bfloat16* KVTb = Kb + (size_t)BB * DD * NN;    // B*C*D bf16
    __hip_bfloat16* Wcat = KVTb + (size_t)BB * CC * DD;  // 128*C bf16
    __hip_bfloat16* xt   = Wcat + 128 * CC;              // B*N*C bf16

    hipMemsetAsync(KX, 0, (size_t)BB * DD * CC * sizeof(float), stream);
    k_wcast<<<dim3(128 * CC / 256), dim3(256), 0, stream>>>(Wq, Wk, Wcat);
    k_xt<<<dim3(NN / 64, CC / 64, BB), dim3(256), 0, stream>>>(x, xt);
    k_proj<<<dim3(NN / 128, BB), dim3(256), 0, stream>>>(xt, Wcat, bq, bk, Qb, Kb);
    k_ksum<<<dim3(BB * DD), dim3(256), 0, stream>>>(Kb, Ksum);
    k_kx<<<dim3(2, 16, BB), dim3(256), 0, stream>>>(Kb, x, KX);
    k_kv<<<dim3(CC / 64, BB), dim3(256), 0, stream>>>(KX, Wv, bv, Ksum, KVTb);
    k_norm<<<dim3(BB * NN / 256), dim3(256), 0, stream>>>(Qb, Ksum, gamma, normv);
    k_out<<<dim3(CC / 128, NN / 128, BB), dim3(256), 0, stream>>>(x, Qb, KVTb, normv, out);
}

// Round 4
// 244.217 us; speedup vs baseline: 3.7019x; 1.1866x over previous
//
#include <hip/hip_runtime.h>
#include <hip/hip_bf16.h>
#include <math.h>

#define BB 16
#define CC 512
#define DD 64
#define NN 4096
#define EPSV 1e-6f

typedef __attribute__((ext_vector_type(8))) short short8;
typedef __attribute__((ext_vector_type(4))) float f32x4;

__device__ __forceinline__ float softplus_f(float v) {
    return fmaxf(v, 0.0f) + log1pf(expf(-fabsf(v)));
}
__device__ __forceinline__ short bf16s(float f) {
    __hip_bfloat16 h = __float2bfloat16(f);
    return __builtin_bit_cast(short, h);
}
__device__ __forceinline__ float sbf16(short s) {
    return __bfloat162float(__builtin_bit_cast(__hip_bfloat16, s));
}

// ---- prep: Wcat bf16 [128][512]  (rows 0-63 = Wq, 64-127 = Wk) ----
__global__ __launch_bounds__(256) void k_wcast(const float* __restrict__ Wq,
                                               const float* __restrict__ Wk,
                                               __hip_bfloat16* __restrict__ Wcat) {
    int i = blockIdx.x * 256 + threadIdx.x;
    if (i < 128 * CC) {
        int j = i >> 9, c = i & 511;
        float v = (j < DD) ? Wq[j * CC + c] : Wk[(j - DD) * CC + c];
        Wcat[i] = __float2bfloat16(v);
    }
}

// ---- prep: xt[b][n][c] bf16 (transpose of x) ----
__global__ __launch_bounds__(256) void k_xt(const float* __restrict__ x,
                                            __hip_bfloat16* __restrict__ xt) {
    int b = blockIdx.z;
    int n0 = blockIdx.x * 64, c0 = blockIdx.y * 64;
    __shared__ float tile[64][65];
    const float* xb = x + ((size_t)b * CC + c0) * NN + n0;
    int t = threadIdx.x;
#pragma unroll
    for (int i = 0; i < 16; ++i) {
        int idx = i * 256 + t;
        int c = idx >> 6, n = idx & 63;
        tile[c][n] = xb[(size_t)c * NN + n];
    }
    __syncthreads();
    __hip_bfloat16* xo = xt + ((size_t)b * NN + n0) * CC + c0;
#pragma unroll
    for (int i = 0; i < 16; ++i) {
        int idx = i * 256 + t;
        int n = idx >> 6, c = idx & 63;
        xo[(size_t)n * CC + c] = __float2bfloat16(tile[c][n]);
    }
}

// ---- Q/K projection via MFMA.  Qb[b][n][d] bf16 ; Kb[b][m][n] bf16 ----
__global__ __launch_bounds__(256) void k_proj(const __hip_bfloat16* __restrict__ xt,
                                              const __hip_bfloat16* __restrict__ Wcat,
                                              const float* __restrict__ bq,
                                              const float* __restrict__ bk,
                                              __hip_bfloat16* __restrict__ Qb,
                                              __hip_bfloat16* __restrict__ Kb) {
    int b = blockIdx.y;
    int n_blk = blockIdx.x * 128;
    int wave = threadIdx.x >> 6;
    int lane = threadIdx.x & 63;
    int n_wave = n_blk + wave * 32;           // wave owns 32 n-rows
    int l16 = lane & 15, g = lane >> 4;

    f32x4 accQ[2][4] = {};                    // D[n][j], j in [0,64)
    f32x4 accK[4][2] = {};                    // D[j][n], j in [64,128)

    const short8* xtp = reinterpret_cast<const short8*>(xt) + ((size_t)b * NN + n_wave) * 64;
    const short8* wp  = reinterpret_cast<const short8*>(Wcat);

    for (int ck = 0; ck < 16; ++ck) {         // 512 c in steps of 32
        int ch = ck * 4 + g;                  // 8-elem chunk index
        short8 xf[2], wf[8];
#pragma unroll
        for (int nf = 0; nf < 2; ++nf) xf[nf] = xtp[(size_t)(nf * 16 + l16) * 64 + ch];
#pragma unroll
        for (int jf = 0; jf < 8; ++jf) wf[jf] = wp[(size_t)(jf * 16 + l16) * 64 + ch];
#pragma unroll
        for (int nf = 0; nf < 2; ++nf)
#pragma unroll
            for (int jf = 0; jf < 4; ++jf)
                accQ[nf][jf] = __builtin_amdgcn_mfma_f32_16x16x32_bf16(xf[nf], wf[jf], accQ[nf][jf], 0, 0, 0);
#pragma unroll
        for (int jf = 0; jf < 4; ++jf)
#pragma unroll
            for (int nf = 0; nf < 2; ++nf)
                accK[jf][nf] = __builtin_amdgcn_mfma_f32_16x16x32_bf16(wf[4 + jf], xf[nf], accK[jf][nf], 0, 0, 0);
    }
    // Q epilogue: row n = n_wave + nf*16 + 4g + r, col j = jf*16 + l16
#pragma unroll
    for (int nf = 0; nf < 2; ++nf)
#pragma unroll
        for (int jf = 0; jf < 4; ++jf)
#pragma unroll
            for (int r = 0; r < 4; ++r) {
                int n = n_wave + nf * 16 + 4 * g + r;
                int j = jf * 16 + l16;
                float v = softplus_f(accQ[nf][jf][r] + bq[j]);
                Qb[((size_t)b * NN + n) * DD + j] = __float2bfloat16(v);
            }
    // K epilogue: row m = jf*16 + 4g + r, col n = n_wave + nf*16 + l16
#pragma unroll
    for (int jf = 0; jf < 4; ++jf)
#pragma unroll
        for (int nf = 0; nf < 2; ++nf)
#pragma unroll
            for (int r = 0; r < 4; ++r) {
                int m = jf * 16 + 4 * g + r;
                int n = n_wave + nf * 16 + l16;
                float v = softplus_f(accK[jf][nf][r] + bk[m]);
                Kb[((size_t)b * DD + m) * NN + n] = __float2bfloat16(v);
            }
}

// ---- Ksum[b*D+m] = sum_n K[b][m][n]  (raw, fp32 accumulate of bf16) ----
__global__ __launch_bounds__(256) void k_ksum(const __hip_bfloat16* __restrict__ Kb,
                                              float* __restrict__ Ksum) {
    int row = blockIdx.x;
    const short8* p = reinterpret_cast<const short8*>(Kb + (size_t)row * NN);
    float s = 0.f;
    for (int i = threadIdx.x; i < NN / 8; i += 256) {
        short8 v = p[i];
#pragma unroll
        for (int e = 0; e < 8; ++e) s += sbf16(v[e]);
    }
    for (int off = 32; off > 0; off >>= 1) s += __shfl_down(s, off, 64);
    __shared__ float red[4];
    if ((threadIdx.x & 63) == 0) red[threadIdx.x >> 6] = s;
    __syncthreads();
    if (threadIdx.x == 0) Ksum[row] = red[0] + red[1] + red[2] + red[3];
}

// ---- KX[b][m][c] += sum_nn Kb[m][nn]*x[c][nn]  (MFMA, no LDS, split-K atomics) ----
__global__ __launch_bounds__(256) void k_kx(const __hip_bfloat16* __restrict__ Kb,
                                            const float* __restrict__ x,
                                            float* __restrict__ KX) {
    int b = blockIdx.z;
    int n0 = blockIdx.y * 256;                // 16 n-chunks
    int c0 = blockIdx.x * 256;                // 2 c-halves
    int wave = threadIdx.x >> 6, lane = threadIdx.x & 63;
    int cw = c0 + wave * 64;                  // wave owns 64 c-cols
    int l16 = lane & 15, g = lane >> 4;

    f32x4 acc[4][4] = {};                     // [mi][cj]
    const __hip_bfloat16* kp = Kb + (size_t)b * DD * NN;
    const float* xp = x + (size_t)b * CC * NN;

#pragma unroll
    for (int ks = 0; ks < 8; ++ks) {          // 256 n in steps of 32
        int nk = n0 + ks * 32 + g * 8;
        short8 af[4];
#pragma unroll
        for (int mi = 0; mi < 4; ++mi)
            af[mi] = *reinterpret_cast<const short8*>(kp + (size_t)(mi * 16 + l16) * NN + nk);
        short8 bf[4];
#pragma unroll
        for (int cj = 0; cj < 4; ++cj) {
            const float* xr = xp + (size_t)(cw + cj * 16 + l16) * NN + nk;
            f32x4 lo = *reinterpret_cast<const f32x4*>(xr);
            f32x4 hi = *reinterpret_cast<const f32x4*>(xr + 4);
            short8 v;
#pragma unroll
            for (int e = 0; e < 4; ++e) { v[e] = bf16s(lo[e]); v[4 + e] = bf16s(hi[e]); }
            bf[cj] = v;
        }
#pragma unroll
        for (int mi = 0; mi < 4; ++mi)
#pragma unroll
            for (int cj = 0; cj < 4; ++cj)
                acc[mi][cj] = __builtin_amdgcn_mfma_f32_16x16x32_bf16(af[mi], bf[cj], acc[mi][cj], 0, 0, 0);
    }
    // D: row m = mi*16 + 4g + r, col c = cw + cj*16 + l16
#pragma unroll
    for (int mi = 0; mi < 4; ++mi)
#pragma unroll
        for (int cj = 0; cj < 4; ++cj)
#pragma unroll
            for (int r = 0; r < 4; ++r) {
                int m = mi * 16 + 4 * g + r;
                int c = cw + cj * 16 + l16;
                atomicAdd(&KX[((size_t)(b * DD + m)) * CC + c], acc[mi][cj][r]);
            }
}

// ---- KVTb[b][c][m] = sum_cp KX[b][m][cp]*Wv[c][cp] + bv[c]*Ksum[b][m]
//      MFMA, no LDS, split hi/lo bf16 for ~fp32 accuracy.
//      A = Wv rows c (cp contiguous), B = KX rows m (cp contiguous)
//      D: row c = cw + 4g + r, col m = mj*16 + l16 ----
__global__ __launch_bounds__(256) void k_kv(const float* __restrict__ KX,
                                            const float* __restrict__ Wv,
                                            const float* __restrict__ bv,
                                            const float* __restrict__ Ksum,
                                            __hip_bfloat16* __restrict__ KVTb) {
    int b = blockIdx.y;
    int c0 = blockIdx.x * 64;
    int wave = threadIdx.x >> 6, lane = threadIdx.x & 63;
    int cw = c0 + wave * 16;                  // wave owns 16 c-rows, all 64 m
    int l16 = lane & 15, g = lane >> 4;

    f32x4 acc[4] = {};                        // [mj]
    const float* wvp = Wv + (size_t)(cw + l16) * CC;
    const float* kxp = KX + (size_t)b * DD * CC;

#pragma unroll
    for (int ck = 0; ck < 16; ++ck) {         // 512 cp in steps of 32
        int cp = ck * 32 + g * 8;
        f32x4 w0 = *reinterpret_cast<const f32x4*>(wvp + cp);
        f32x4 w1 = *reinterpret_cast<const f32x4*>(wvp + cp + 4);
        short8 a_hi, a_lo;
#pragma unroll
        for (int e = 0; e < 4; ++e) {
            a_hi[e] = bf16s(w0[e]);     a_lo[e] = bf16s(w0[e] - sbf16(a_hi[e]));
            a_hi[4 + e] = bf16s(w1[e]); a_lo[4 + e] = bf16s(w1[e] - sbf16(a_hi[4 + e]));
        }
#pragma unroll
        for (int mj = 0; mj < 4; ++mj) {
            const float* kr = kxp + (size_t)(mj * 16 + l16) * CC + cp;
            f32x4 k0 = *reinterpret_cast<const f32x4*>(kr);
            f32x4 k1 = *reinterpret_cast<const f32x4*>(kr + 4);
            short8 b_hi, b_lo;
#pragma unroll
            for (int e = 0; e < 4; ++e) {
                b_hi[e] = bf16s(k0[e]);     b_lo[e] = bf16s(k0[e] - sbf16(b_hi[e]));
                b_hi[4 + e] = bf16s(k1[e]); b_lo[4 + e] = bf16s(k1[e] - sbf16(b_hi[4 + e]));
            }
            acc[mj] = __builtin_amdgcn_mfma_f32_16x16x32_bf16(a_hi, b_hi, acc[mj], 0, 0, 0);
            acc[mj] = __builtin_amdgcn_mfma_f32_16x16x32_bf16(a_lo, b_hi, acc[mj], 0, 0, 0);
            acc[mj] = __builtin_amdgcn_mfma_f32_16x16x32_bf16(a_hi, b_lo, acc[mj], 0, 0, 0);
        }
    }
#pragma unroll
    for (int mj = 0; mj < 4; ++mj)
#pragma unroll
        for (int r = 0; r < 4; ++r) {
            int c = cw + 4 * g + r;
            int m = mj * 16 + l16;
            KVTb[((size_t)b * CC + c) * DD + m] =
                __float2bfloat16(acc[mj][r] + bv[c] * Ksum[b * DD + m]);
        }
}

// ---- normv[b*N+n] = gamma / sum_m Q[n][m]*(Ksum[m]+eps) ----
__global__ __launch_bounds__(256) void k_norm(const __hip_bfloat16* __restrict__ Qb,
                                              const float* __restrict__ Ksum,
                                              const float* __restrict__ gamma,
                                              float* __restrict__ normv) {
    int i = blockIdx.x * 256 + threadIdx.x;   // i = b*N + n
    int b = i >> 12;
    const short8* q = reinterpret_cast<const short8*>(Qb + (size_t)i * DD);
    const float* ks = Ksum + b * DD;
    float dot = 0.f;
#pragma unroll
    for (int v8 = 0; v8 < 8; ++v8) {
        short8 v = q[v8];
#pragma unroll
        for (int e = 0; e < 8; ++e) dot = fmaf(sbf16(v[e]), ks[v8 * 8 + e] + EPSV, dot);
    }
    normv[i] = gamma[0] / dot;
}

// ---- out[c][n] = x + normv[n] * sum_m KVT[c][m]*Q[n][m]   (MFMA, K=64) ----
__global__ __launch_bounds__(256) void k_out(const float* __restrict__ x,
                                             const __hip_bfloat16* __restrict__ Qb,
                                             const __hip_bfloat16* __restrict__ KVTb,
                                             const float* __restrict__ normv,
                                             float* __restrict__ out) {
    int b = blockIdx.z;
    int c_blk = blockIdx.x * 128, n_blk = blockIdx.y * 128;
    int wave = threadIdx.x >> 6, lane = threadIdx.x & 63;
    int cw = c_blk + (wave >> 1) * 64, nw = n_blk + (wave & 1) * 64;
    int l16 = lane & 15, g = lane >> 4;

    f32x4 acc[4][4] = {};
    const short8* ap = reinterpret_cast<const short8*>(KVTb) + ((size_t)b * CC + cw) * 8;
    const short8* bp = reinterpret_cast<const short8*>(Qb) + ((size_t)b * NN + nw) * 8;
#pragma unroll
    for (int ck = 0; ck < 2; ++ck) {
        int ch = ck * 4 + g;
        short8 af[4], bf[4];
#pragma unroll
        for (int i = 0; i < 4; ++i) af[i] = ap[(size_t)(i * 16 + l16) * 8 + ch];
#pragma unroll
        for (int i = 0; i < 4; ++i) bf[i] = bp[(size_t)(i * 16 + l16) * 8 + ch];
#pragma unroll
        for (int i = 0; i < 4; ++i)
#pragma unroll
            for (int j = 0; j < 4; ++j)
                acc[i][j] = __builtin_amdgcn_mfma_f32_16x16x32_bf16(af[i], bf[j], acc[i][j], 0, 0, 0);
    }
    float sc[4];
#pragma unroll
    for (int j = 0; j < 4; ++j) sc[j] = normv[(size_t)b * NN + nw + j * 16 + l16];
    const float* xb = x + (size_t)b * CC * NN;
    float* ob = out + (size_t)b * CC * NN;
#pragma unroll
    for (int i = 0; i < 4; ++i)
#pragma unroll
        for (int r = 0; r < 4; ++r) {
            int c = cw + i * 16 + 4 * g + r;
            size_t rowoff = (size_t)c * NN;
#pragma unroll
            for (int j = 0; j < 4; ++j) {
                int n = nw + j * 16 + l16;
                ob[rowoff + n] = xb[rowoff + n] + sc[j] * acc[i][j][r];
            }
        }
}

extern "C" void kernel_launch(void* const* d_in, const int* in_sizes, int n_in,
                              void* d_out, int out_size, void* d_ws, size_t ws_size,
                              hipStream_t stream) {
    const float* x     = (const float*)d_in[0];
    const float* Wq    = (const float*)d_in[1];
    const float* bq    = (const float*)d_in[2];
    const float* Wk    = (const float*)d_in[3];
    const float* bk    = (const float*)d_in[4];
    const float* Wv    = (const float*)d_in[5];
    const float* bv    = (const float*)d_in[6];
    const float* gamma = (const float*)d_in[7];
    float* out = (float*)d_out;

    float* ws    = (float*)d_ws;
    float* KX    = ws;                                   // B*D*C fp32
    float* Ksum  = KX + (size_t)BB * DD * CC;            // B*D fp32
    float* normv = Ksum + BB * DD;                       // B*N fp32
    __hip_bfloat16* Qb   = (__hip_bfloat16*)(normv + (size_t)BB * NN);  // B*N*D bf16
    __hip_bfloat16* Kb   = Qb + (size_t)BB * NN * DD;    // B*D*N bf16
    __hip_bfloat16* KVTb = Kb + (size_t)BB * DD * NN;    // B*C*D bf16
    __hip_bfloat16* Wcat = KVTb + (size_t)BB * CC * DD;  // 128*C bf16
    __hip_bfloat16* xt   = Wcat + 128 * CC;              // B*N*C bf16

    hipMemsetAsync(KX, 0, (size_t)BB * DD * CC * sizeof(float), stream);
    k_wcast<<<dim3(128 * CC / 256), dim3(256), 0, stream>>>(Wq, Wk, Wcat);
    k_xt<<<dim3(NN / 64, CC / 64, BB), dim3(256), 0, stream>>>(x, xt);
    k_proj<<<dim3(NN / 128, BB), dim3(256), 0, stream>>>(xt, Wcat, bq, bk, Qb, Kb);
    k_ksum<<<dim3(BB * DD), dim3(256), 0, stream>>>(Kb, Ksum);
    k_kx<<<dim3(2, 16, BB), dim3(256), 0, stream>>>(Kb, x, KX);
    k_kv<<<dim3(CC / 64, BB), dim3(256), 0, stream>>>(KX, Wv, bv, Ksum, KVTb);
    k_norm<<<dim3(BB * NN / 256), dim3(256), 0, stream>>>(Qb, Ksum, gamma, normv);
    k_out<<<dim3(CC / 128, NN / 128, BB), dim3(256), 0, stream>>>(x, Qb, KVTb, normv, out);
}

// Round 5
// 241.705 us; speedup vs baseline: 3.7404x; 1.0104x over previous
//
#include <hip/hip_runtime.h>
#include <hip/hip_bf16.h>
#include <math.h>

#define BB 16
#define CC 512
#define DD 64
#define NN 4096
#define EPSV 1e-6f

typedef __attribute__((ext_vector_type(8))) short short8;
typedef __attribute__((ext_vector_type(4))) float f32x4;

__device__ __forceinline__ float softplus_f(float v) {
    return fmaxf(v, 0.0f) + log1pf(expf(-fabsf(v)));
}
__device__ __forceinline__ short bf16s(float f) {
    __hip_bfloat16 h = __float2bfloat16(f);
    return __builtin_bit_cast(short, h);
}
__device__ __forceinline__ float sbf16(short s) {
    return __bfloat162float(__builtin_bit_cast(__hip_bfloat16, s));
}

// ---- prep: Wcat bf16 [128][512] (blocks 0-255) + zero KX (blocks 256-767) ----
__global__ __launch_bounds__(256) void k_prep(const float* __restrict__ Wq,
                                              const float* __restrict__ Wk,
                                              __hip_bfloat16* __restrict__ Wcat,
                                              float* __restrict__ KX) {
    int blk = blockIdx.x;
    if (blk < 256) {
        int i = blk * 256 + threadIdx.x;
        int j = i >> 9, c = i & 511;
        float v = (j < DD) ? Wq[j * CC + c] : Wk[(j - DD) * CC + c];
        Wcat[i] = __float2bfloat16(v);
    } else {
        int i = (blk - 256) * 256 + threadIdx.x;   // 512 blocks * 256 threads * 4 floats
        f32x4 z = {0.f, 0.f, 0.f, 0.f};
        reinterpret_cast<f32x4*>(KX)[i] = z;
    }
}

// ---- prep: xt[b][n][c] bf16 (transpose of x) ----
__global__ __launch_bounds__(256) void k_xt(const float* __restrict__ x,
                                            __hip_bfloat16* __restrict__ xt) {
    int b = blockIdx.z;
    int n0 = blockIdx.x * 64, c0 = blockIdx.y * 64;
    __shared__ float tile[64][65];
    const float* xb = x + ((size_t)b * CC + c0) * NN + n0;
    int t = threadIdx.x;
#pragma unroll
    for (int i = 0; i < 16; ++i) {
        int idx = i * 256 + t;
        int c = idx >> 6, n = idx & 63;
        tile[c][n] = xb[(size_t)c * NN + n];
    }
    __syncthreads();
    __hip_bfloat16* xo = xt + ((size_t)b * NN + n0) * CC + c0;
#pragma unroll
    for (int i = 0; i < 16; ++i) {
        int idx = i * 256 + t;
        int n = idx >> 6, c = idx & 63;
        xo[(size_t)n * CC + c] = __float2bfloat16(tile[c][n]);
    }
}

// ---- Q/K projection via MFMA.  Qb[b][n][d] bf16 ; Kb[b][m][n] bf16 ----
__global__ __launch_bounds__(256) void k_proj(const __hip_bfloat16* __restrict__ xt,
                                              const __hip_bfloat16* __restrict__ Wcat,
                                              const float* __restrict__ bq,
                                              const float* __restrict__ bk,
                                              __hip_bfloat16* __restrict__ Qb,
                                              __hip_bfloat16* __restrict__ Kb) {
    int b = blockIdx.y;
    int n_blk = blockIdx.x * 128;
    int wave = threadIdx.x >> 6;
    int lane = threadIdx.x & 63;
    int n_wave = n_blk + wave * 32;           // wave owns 32 n-rows
    int l16 = lane & 15, g = lane >> 4;

    f32x4 accQ[2][4] = {};                    // D[n][j], j in [0,64)
    f32x4 accK[4][2] = {};                    // D[j][n], j in [64,128)

    const short8* xtp = reinterpret_cast<const short8*>(xt) + ((size_t)b * NN + n_wave) * 64;
    const short8* wp  = reinterpret_cast<const short8*>(Wcat);

    for (int ck = 0; ck < 16; ++ck) {         // 512 c in steps of 32
        int ch = ck * 4 + g;                  // 8-elem chunk index
        short8 xf[2], wf[8];
#pragma unroll
        for (int nf = 0; nf < 2; ++nf) xf[nf] = xtp[(size_t)(nf * 16 + l16) * 64 + ch];
#pragma unroll
        for (int jf = 0; jf < 8; ++jf) wf[jf] = wp[(size_t)(jf * 16 + l16) * 64 + ch];
#pragma unroll
        for (int nf = 0; nf < 2; ++nf)
#pragma unroll
            for (int jf = 0; jf < 4; ++jf)
                accQ[nf][jf] = __builtin_amdgcn_mfma_f32_16x16x32_bf16(xf[nf], wf[jf], accQ[nf][jf], 0, 0, 0);
#pragma unroll
        for (int jf = 0; jf < 4; ++jf)
#pragma unroll
            for (int nf = 0; nf < 2; ++nf)
                accK[jf][nf] = __builtin_amdgcn_mfma_f32_16x16x32_bf16(wf[4 + jf], xf[nf], accK[jf][nf], 0, 0, 0);
    }
    // Q epilogue: row n = n_wave + nf*16 + 4g + r, col j = jf*16 + l16
#pragma unroll
    for (int nf = 0; nf < 2; ++nf)
#pragma unroll
        for (int jf = 0; jf < 4; ++jf)
#pragma unroll
            for (int r = 0; r < 4; ++r) {
                int n = n_wave + nf * 16 + 4 * g + r;
                int j = jf * 16 + l16;
                float v = softplus_f(accQ[nf][jf][r] + bq[j]);
                Qb[((size_t)b * NN + n) * DD + j] = __float2bfloat16(v);
            }
    // K epilogue: row m = jf*16 + 4g + r, col n = n_wave + nf*16 + l16
#pragma unroll
    for (int jf = 0; jf < 4; ++jf)
#pragma unroll
        for (int nf = 0; nf < 2; ++nf)
#pragma unroll
            for (int r = 0; r < 4; ++r) {
                int m = jf * 16 + 4 * g + r;
                int n = n_wave + nf * 16 + l16;
                float v = softplus_f(accK[jf][nf][r] + bk[m]);
                Kb[((size_t)b * DD + m) * NN + n] = __float2bfloat16(v);
            }
}

// ---- Ksum[b*D+m] = sum_n K[b][m][n]  (raw, fp32 accumulate of bf16) ----
__global__ __launch_bounds__(256) void k_ksum(const __hip_bfloat16* __restrict__ Kb,
                                              float* __restrict__ Ksum) {
    int row = blockIdx.x;
    const short8* p = reinterpret_cast<const short8*>(Kb + (size_t)row * NN);
    float s = 0.f;
    for (int i = threadIdx.x; i < NN / 8; i += 256) {
        short8 v = p[i];
#pragma unroll
        for (int e = 0; e < 8; ++e) s += sbf16(v[e]);
    }
    for (int off = 32; off > 0; off >>= 1) s += __shfl_down(s, off, 64);
    __shared__ float red[4];
    if ((threadIdx.x & 63) == 0) red[threadIdx.x >> 6] = s;
    __syncthreads();
    if (threadIdx.x == 0) Ksum[row] = red[0] + red[1] + red[2] + red[3];
}

// ---- KX[b][m][c] += sum_nn Kb[m][nn]*x[c][nn]  (MFMA, no LDS, split-K atomics) ----
__global__ __launch_bounds__(256) void k_kx(const __hip_bfloat16* __restrict__ Kb,
                                            const float* __restrict__ x,
                                            float* __restrict__ KX) {
    int b = blockIdx.z;
    int n0 = blockIdx.y * 256;                // 16 n-chunks
    int c0 = blockIdx.x * 256;                // 2 c-halves
    int wave = threadIdx.x >> 6, lane = threadIdx.x & 63;
    int cw = c0 + wave * 64;                  // wave owns 64 c-cols
    int l16 = lane & 15, g = lane >> 4;

    f32x4 acc[4][4] = {};                     // [mi][cj]
    const __hip_bfloat16* kp = Kb + (size_t)b * DD * NN;
    const float* xp = x + (size_t)b * CC * NN;

#pragma unroll
    for (int ks = 0; ks < 8; ++ks) {          // 256 n in steps of 32
        int nk = n0 + ks * 32 + g * 8;
        short8 af[4];
#pragma unroll
        for (int mi = 0; mi < 4; ++mi)
            af[mi] = *reinterpret_cast<const short8*>(kp + (size_t)(mi * 16 + l16) * NN + nk);
        short8 bf[4];
#pragma unroll
        for (int cj = 0; cj < 4; ++cj) {
            const float* xr = xp + (size_t)(cw + cj * 16 + l16) * NN + nk;
            f32x4 lo = *reinterpret_cast<const f32x4*>(xr);
            f32x4 hi = *reinterpret_cast<const f32x4*>(xr + 4);
            short8 v;
#pragma unroll
            for (int e = 0; e < 4; ++e) { v[e] = bf16s(lo[e]); v[4 + e] = bf16s(hi[e]); }
            bf[cj] = v;
        }
#pragma unroll
        for (int mi = 0; mi < 4; ++mi)
#pragma unroll
            for (int cj = 0; cj < 4; ++cj)
                acc[mi][cj] = __builtin_amdgcn_mfma_f32_16x16x32_bf16(af[mi], bf[cj], acc[mi][cj], 0, 0, 0);
    }
    // D: row m = mi*16 + 4g + r, col c = cw + cj*16 + l16
#pragma unroll
    for (int mi = 0; mi < 4; ++mi)
#pragma unroll
        for (int cj = 0; cj < 4; ++cj)
#pragma unroll
            for (int r = 0; r < 4; ++r) {
                int m = mi * 16 + 4 * g + r;
                int c = cw + cj * 16 + l16;
                atomicAdd(&KX[((size_t)(b * DD + m)) * CC + c], acc[mi][cj][r]);
            }
}

// ---- KVTb[b][c][m] = sum_cp KX[b][m][cp]*Wv[c][cp] + bv[c]*Ksum[b][m]
//      MFMA, no LDS, split hi/lo bf16 for ~fp32 accuracy. ----
__global__ __launch_bounds__(256) void k_kv(const float* __restrict__ KX,
                                            const float* __restrict__ Wv,
                                            const float* __restrict__ bv,
                                            const float* __restrict__ Ksum,
                                            __hip_bfloat16* __restrict__ KVTb) {
    int b = blockIdx.y;
    int c0 = blockIdx.x * 64;
    int wave = threadIdx.x >> 6, lane = threadIdx.x & 63;
    int cw = c0 + wave * 16;                  // wave owns 16 c-rows, all 64 m
    int l16 = lane & 15, g = lane >> 4;

    f32x4 acc[4] = {};                        // [mj]
    const float* wvp = Wv + (size_t)(cw + l16) * CC;
    const float* kxp = KX + (size_t)b * DD * CC;

#pragma unroll
    for (int ck = 0; ck < 16; ++ck) {         // 512 cp in steps of 32
        int cp = ck * 32 + g * 8;
        f32x4 w0 = *reinterpret_cast<const f32x4*>(wvp + cp);
        f32x4 w1 = *reinterpret_cast<const f32x4*>(wvp + cp + 4);
        short8 a_hi, a_lo;
#pragma unroll
        for (int e = 0; e < 4; ++e) {
            a_hi[e] = bf16s(w0[e]);     a_lo[e] = bf16s(w0[e] - sbf16(a_hi[e]));
            a_hi[4 + e] = bf16s(w1[e]); a_lo[4 + e] = bf16s(w1[e] - sbf16(a_hi[4 + e]));
        }
#pragma unroll
        for (int mj = 0; mj < 4; ++mj) {
            const float* kr = kxp + (size_t)(mj * 16 + l16) * CC + cp;
            f32x4 k0 = *reinterpret_cast<const f32x4*>(kr);
            f32x4 k1 = *reinterpret_cast<const f32x4*>(kr + 4);
            short8 b_hi, b_lo;
#pragma unroll
            for (int e = 0; e < 4; ++e) {
                b_hi[e] = bf16s(k0[e]);     b_lo[e] = bf16s(k0[e] - sbf16(b_hi[e]));
                b_hi[4 + e] = bf16s(k1[e]); b_lo[4 + e] = bf16s(k1[e] - sbf16(b_hi[4 + e]));
            }
            acc[mj] = __builtin_amdgcn_mfma_f32_16x16x32_bf16(a_hi, b_hi, acc[mj], 0, 0, 0);
            acc[mj] = __builtin_amdgcn_mfma_f32_16x16x32_bf16(a_lo, b_hi, acc[mj], 0, 0, 0);
            acc[mj] = __builtin_amdgcn_mfma_f32_16x16x32_bf16(a_hi, b_lo, acc[mj], 0, 0, 0);
        }
    }
#pragma unroll
    for (int mj = 0; mj < 4; ++mj)
#pragma unroll
        for (int r = 0; r < 4; ++r) {
            int c = cw + 4 * g + r;
            int m = mj * 16 + l16;
            KVTb[((size_t)b * CC + c) * DD + m] =
                __float2bfloat16(acc[mj][r] + bv[c] * Ksum[b * DD + m]);
        }
}

// ---- normv[b*N+n] = gamma / sum_m Q[n][m]*(Ksum[m]+eps) ----
__global__ __launch_bounds__(256) void k_norm(const __hip_bfloat16* __restrict__ Qb,
                                              const float* __restrict__ Ksum,
                                              const float* __restrict__ gamma,
                                              float* __restrict__ normv) {
    int i = blockIdx.x * 256 + threadIdx.x;   // i = b*N + n
    int b = i >> 12;
    const short8* q = reinterpret_cast<const short8*>(Qb + (size_t)i * DD);
    const float* ks = Ksum + b * DD;
    float dot = 0.f;
#pragma unroll
    for (int v8 = 0; v8 < 8; ++v8) {
        short8 v = q[v8];
#pragma unroll
        for (int e = 0; e < 8; ++e) dot = fmaf(sbf16(v[e]), ks[v8 * 8 + e] + EPSV, dot);
    }
    normv[i] = gamma[0] / dot;
}

// ---- out[c][n] = x + normv[n] * sum_m KVT[c][m]*Q[n][m]   (MFMA, K=64) ----
__global__ __launch_bounds__(256) void k_out(const float* __restrict__ x,
                                             const __hip_bfloat16* __restrict__ Qb,
                                             const __hip_bfloat16* __restrict__ KVTb,
                                             const float* __restrict__ normv,
                                             float* __restrict__ out) {
    int b = blockIdx.z;
    int c_blk = blockIdx.x * 128, n_blk = blockIdx.y * 128;
    int wave = threadIdx.x >> 6, lane = threadIdx.x & 63;
    int cw = c_blk + (wave >> 1) * 64, nw = n_blk + (wave & 1) * 64;
    int l16 = lane & 15, g = lane >> 4;

    f32x4 acc[4][4] = {};
    const short8* ap = reinterpret_cast<const short8*>(KVTb) + ((size_t)b * CC + cw) * 8;
    const short8* bp = reinterpret_cast<const short8*>(Qb) + ((size_t)b * NN + nw) * 8;
#pragma unroll
    for (int ck = 0; ck < 2; ++ck) {
        int ch = ck * 4 + g;
        short8 af[4], bf[4];
#pragma unroll
        for (int i = 0; i < 4; ++i) af[i] = ap[(size_t)(i * 16 + l16) * 8 + ch];
#pragma unroll
        for (int i = 0; i < 4; ++i) bf[i] = bp[(size_t)(i * 16 + l16) * 8 + ch];
#pragma unroll
        for (int i = 0; i < 4; ++i)
#pragma unroll
            for (int j = 0; j < 4; ++j)
                acc[i][j] = __builtin_amdgcn_mfma_f32_16x16x32_bf16(af[i], bf[j], acc[i][j], 0, 0, 0);
    }
    float sc[4];
#pragma unroll
    for (int j = 0; j < 4; ++j) sc[j] = normv[(size_t)b * NN + nw + j * 16 + l16];
    const float* xb = x + (size_t)b * CC * NN;
    float* ob = out + (size_t)b * CC * NN;
#pragma unroll
    for (int i = 0; i < 4; ++i)
#pragma unroll
        for (int r = 0; r < 4; ++r) {
            int c = cw + i * 16 + 4 * g + r;
            size_t rowoff = (size_t)c * NN;
#pragma unroll
            for (int j = 0; j < 4; ++j) {
                int n = nw + j * 16 + l16;
                ob[rowoff + n] = xb[rowoff + n] + sc[j] * acc[i][j][r];
            }
        }
}

extern "C" void kernel_launch(void* const* d_in, const int* in_sizes, int n_in,
                              void* d_out, int out_size, void* d_ws, size_t ws_size,
                              hipStream_t stream) {
    const float* x     = (const float*)d_in[0];
    const float* Wq    = (const float*)d_in[1];
    const float* bq    = (const float*)d_in[2];
    const float* Wk    = (const float*)d_in[3];
    const float* bk    = (const float*)d_in[4];
    const float* Wv    = (const float*)d_in[5];
    const float* bv    = (const float*)d_in[6];
    const float* gamma = (const float*)d_in[7];
    float* out = (float*)d_out;

    float* ws    = (float*)d_ws;
    float* KX    = ws;                                   // B*D*C fp32
    float* Ksum  = KX + (size_t)BB * DD * CC;            // B*D fp32
    float* normv = Ksum + BB * DD;                       // B*N fp32
    __hip_bfloat16* Qb   = (__hip_bfloat16*)(normv + (size_t)BB * NN);  // B*N*D bf16
    __hip_bfloat16* Kb   = Qb + (size_t)BB * NN * DD;    // B*D*N bf16
    __hip_bfloat16* KVTb = Kb + (size_t)BB * DD * NN;    // B*C*D bf16
    __hip_bfloat16* Wcat = KVTb + (size_t)BB * CC * DD;  // 128*C bf16
    __hip_bfloat16* xt   = Wcat + 128 * CC;              // B*N*C bf16

    k_prep<<<dim3(768), dim3(256), 0, stream>>>(Wq, Wk, Wcat, KX);
    k_xt<<<dim3(NN / 64, CC / 64, BB), dim3(256), 0, stream>>>(x, xt);
    k_proj<<<dim3(NN / 128, BB), dim3(256), 0, stream>>>(xt, Wcat, bq, bk, Qb, Kb);
    k_ksum<<<dim3(BB * DD), dim3(256), 0, stream>>>(Kb, Ksum);
    k_kx<<<dim3(2, 16, BB), dim3(256), 0, stream>>>(Kb, x, KX);
    k_kv<<<dim3(CC / 64, BB), dim3(256), 0, stream>>>(KX, Wv, bv, Ksum, KVTb);
    k_norm<<<dim3(BB * NN / 256), dim3(256), 0, stream>>>(Qb, Ksum, gamma, normv);
    k_out<<<dim3(CC / 128, NN / 128, BB), dim3(256), 0, stream>>>(x, Qb, KVTb, normv, out);
}

// Round 6
// 214.741 us; speedup vs baseline: 4.2101x; 1.1256x over previous
//
#include <hip/hip_runtime.h>
#include <hip/hip_bf16.h>
#include <math.h>

#define BB 16
#define CC 512
#define DD 64
#define NN 4096
#define EPSV 1e-6f

typedef __attribute__((ext_vector_type(8))) short short8;
typedef __attribute__((ext_vector_type(4))) float f32x4;

__device__ __forceinline__ float softplus_f(float v) {
    return fmaxf(v, 0.0f) + log1pf(expf(-fabsf(v)));
}
__device__ __forceinline__ short bf16s(float f) {
    __hip_bfloat16 h = __float2bfloat16(f);
    return __builtin_bit_cast(short, h);
}
__device__ __forceinline__ float sbf16(short s) {
    return __bfloat162float(__builtin_bit_cast(__hip_bfloat16, s));
}

// ---- prep: Wcat bf16 [128][512] (blocks 0-255), zero KX (256-767), zero Ksum (768) ----
__global__ __launch_bounds__(256) void k_prep(const float* __restrict__ Wq,
                                              const float* __restrict__ Wk,
                                              __hip_bfloat16* __restrict__ Wcat,
                                              float* __restrict__ KX,
                                              float* __restrict__ Ksum) {
    int blk = blockIdx.x;
    if (blk < 256) {
        int i = blk * 256 + threadIdx.x;
        int j = i >> 9, c = i & 511;
        float v = (j < DD) ? Wq[j * CC + c] : Wk[(j - DD) * CC + c];
        Wcat[i] = __float2bfloat16(v);
    } else if (blk < 768) {
        int i = (blk - 256) * 256 + threadIdx.x;   // 512*256 f32x4 = 2MB
        f32x4 z = {0.f, 0.f, 0.f, 0.f};
        reinterpret_cast<f32x4*>(KX)[i] = z;
    } else {
        f32x4 z = {0.f, 0.f, 0.f, 0.f};
        reinterpret_cast<f32x4*>(Ksum)[threadIdx.x] = z;  // 1024 floats
    }
}

// ---- Q/K projection via MFMA, x read DIRECT from global (no transpose buffer).
//      Also accumulates Ksum[b][m] via wave-reduce + atomics.
//      Qb[b][n][d] bf16 ; Kb[b][m][n] bf16 ----
__global__ __launch_bounds__(256) void k_proj(const float* __restrict__ x,
                                              const __hip_bfloat16* __restrict__ Wcat,
                                              const float* __restrict__ bq,
                                              const float* __restrict__ bk,
                                              __hip_bfloat16* __restrict__ Qb,
                                              __hip_bfloat16* __restrict__ Kb,
                                              float* __restrict__ Ksum) {
    int b = blockIdx.y;
    int n_blk = blockIdx.x * 128;
    int wave = threadIdx.x >> 6;
    int lane = threadIdx.x & 63;
    int n_wave = n_blk + wave * 32;           // wave owns 32 n-rows
    int l16 = lane & 15, g = lane >> 4;

    f32x4 accQ[2][4] = {};                    // Q: D[n][j]
    f32x4 accK[4][2] = {};                    // K: D[j][n]

    const short8* wp = reinterpret_cast<const short8*>(Wcat);
    const float* xc = x + (size_t)b * CC * NN + (n_wave + l16);   // column base, this lane's n (nf=0)

    for (int ck = 0; ck < 16; ++ck) {         // 512 c in steps of 32
        int ch = ck * 4 + g;                  // 8-elem chunk index
        int cbase = ch * 8;
        short8 xf[2], wf[8];
#pragma unroll
        for (int nf = 0; nf < 2; ++nf) {
            const float* xp = xc + nf * 16;
            short8 v;
#pragma unroll
            for (int e = 0; e < 8; ++e) v[e] = bf16s(xp[(size_t)(cbase + e) * NN]);
            xf[nf] = v;
        }
#pragma unroll
        for (int jf = 0; jf < 8; ++jf) wf[jf] = wp[(size_t)(jf * 16 + l16) * 64 + ch];
#pragma unroll
        for (int nf = 0; nf < 2; ++nf)
#pragma unroll
            for (int jf = 0; jf < 4; ++jf)
                accQ[nf][jf] = __builtin_amdgcn_mfma_f32_16x16x32_bf16(xf[nf], wf[jf], accQ[nf][jf], 0, 0, 0);
#pragma unroll
        for (int jf = 0; jf < 4; ++jf)
#pragma unroll
            for (int nf = 0; nf < 2; ++nf)
                accK[jf][nf] = __builtin_amdgcn_mfma_f32_16x16x32_bf16(wf[4 + jf], xf[nf], accK[jf][nf], 0, 0, 0);
    }
    // Q epilogue: row n = n_wave + nf*16 + 4g + r, col j = jf*16 + l16
#pragma unroll
    for (int nf = 0; nf < 2; ++nf)
#pragma unroll
        for (int jf = 0; jf < 4; ++jf)
#pragma unroll
            for (int r = 0; r < 4; ++r) {
                int n = n_wave + nf * 16 + 4 * g + r;
                int j = jf * 16 + l16;
                float v = softplus_f(accQ[nf][jf][r] + bq[j]);
                Qb[((size_t)b * NN + n) * DD + j] = __float2bfloat16(v);
            }
    // K epilogue: row m = jf*16 + 4g + r, col n = n_wave + nf*16 + l16; fused Ksum
#pragma unroll
    for (int jf = 0; jf < 4; ++jf)
#pragma unroll
        for (int r = 0; r < 4; ++r) {
            int m = jf * 16 + 4 * g + r;
            float s = 0.f;
#pragma unroll
            for (int nf = 0; nf < 2; ++nf) {
                int n = n_wave + nf * 16 + l16;
                float v = softplus_f(accK[jf][nf][r] + bk[m]);
                Kb[((size_t)b * DD + m) * NN + n] = __float2bfloat16(v);
                s += v;
            }
            s += __shfl_xor(s, 1, 64);
            s += __shfl_xor(s, 2, 64);
            s += __shfl_xor(s, 4, 64);
            s += __shfl_xor(s, 8, 64);
            if (l16 == 0) atomicAdd(&Ksum[b * DD + m], s);
        }
}

// ---- KX[b][m][c] += sum_nn Kb[m][nn]*x[c][nn]  (MFMA, no LDS, split-K atomics) ----
__global__ __launch_bounds__(256) void k_kx(const __hip_bfloat16* __restrict__ Kb,
                                            const float* __restrict__ x,
                                            float* __restrict__ KX) {
    int b = blockIdx.z;
    int n0 = blockIdx.y * 256;                // 16 n-chunks
    int c0 = blockIdx.x * 256;                // 2 c-halves
    int wave = threadIdx.x >> 6, lane = threadIdx.x & 63;
    int cw = c0 + wave * 64;                  // wave owns 64 c-cols
    int l16 = lane & 15, g = lane >> 4;

    f32x4 acc[4][4] = {};                     // [mi][cj]
    const __hip_bfloat16* kp = Kb + (size_t)b * DD * NN;
    const float* xp = x + (size_t)b * CC * NN;

#pragma unroll
    for (int ks = 0; ks < 8; ++ks) {          // 256 n in steps of 32
        int nk = n0 + ks * 32 + g * 8;
        short8 af[4];
#pragma unroll
        for (int mi = 0; mi < 4; ++mi)
            af[mi] = *reinterpret_cast<const short8*>(kp + (size_t)(mi * 16 + l16) * NN + nk);
        short8 bf[4];
#pragma unroll
        for (int cj = 0; cj < 4; ++cj) {
            const float* xr = xp + (size_t)(cw + cj * 16 + l16) * NN + nk;
            f32x4 lo = *reinterpret_cast<const f32x4*>(xr);
            f32x4 hi = *reinterpret_cast<const f32x4*>(xr + 4);
            short8 v;
#pragma unroll
            for (int e = 0; e < 4; ++e) { v[e] = bf16s(lo[e]); v[4 + e] = bf16s(hi[e]); }
            bf[cj] = v;
        }
#pragma unroll
        for (int mi = 0; mi < 4; ++mi)
#pragma unroll
            for (int cj = 0; cj < 4; ++cj)
                acc[mi][cj] = __builtin_amdgcn_mfma_f32_16x16x32_bf16(af[mi], bf[cj], acc[mi][cj], 0, 0, 0);
    }
#pragma unroll
    for (int mi = 0; mi < 4; ++mi)
#pragma unroll
        for (int cj = 0; cj < 4; ++cj)
#pragma unroll
            for (int r = 0; r < 4; ++r) {
                int m = mi * 16 + 4 * g + r;
                int c = cw + cj * 16 + l16;
                atomicAdd(&KX[((size_t)(b * DD + m)) * CC + c], acc[mi][cj][r]);
            }
}

// ---- KVTb[b][c][m] = sum_cp KX[b][m][cp]*Wv[c][cp] + bv[c]*Ksum[b][m]
//      MFMA, no LDS, split hi/lo bf16 for ~fp32 accuracy. ----
__global__ __launch_bounds__(256) void k_kv(const float* __restrict__ KX,
                                            const float* __restrict__ Wv,
                                            const float* __restrict__ bv,
                                            const float* __restrict__ Ksum,
                                            __hip_bfloat16* __restrict__ KVTb) {
    int b = blockIdx.y;
    int c0 = blockIdx.x * 64;
    int wave = threadIdx.x >> 6, lane = threadIdx.x & 63;
    int cw = c0 + wave * 16;                  // wave owns 16 c-rows, all 64 m
    int l16 = lane & 15, g = lane >> 4;

    f32x4 acc[4] = {};                        // [mj]
    const float* wvp = Wv + (size_t)(cw + l16) * CC;
    const float* kxp = KX + (size_t)b * DD * CC;

#pragma unroll
    for (int ck = 0; ck < 16; ++ck) {         // 512 cp in steps of 32
        int cp = ck * 32 + g * 8;
        f32x4 w0 = *reinterpret_cast<const f32x4*>(wvp + cp);
        f32x4 w1 = *reinterpret_cast<const f32x4*>(wvp + cp + 4);
        short8 a_hi, a_lo;
#pragma unroll
        for (int e = 0; e < 4; ++e) {
            a_hi[e] = bf16s(w0[e]);     a_lo[e] = bf16s(w0[e] - sbf16(a_hi[e]));
            a_hi[4 + e] = bf16s(w1[e]); a_lo[4 + e] = bf16s(w1[e] - sbf16(a_hi[4 + e]));
        }
#pragma unroll
        for (int mj = 0; mj < 4; ++mj) {
            const float* kr = kxp + (size_t)(mj * 16 + l16) * CC + cp;
            f32x4 k0 = *reinterpret_cast<const f32x4*>(kr);
            f32x4 k1 = *reinterpret_cast<const f32x4*>(kr + 4);
            short8 b_hi, b_lo;
#pragma unroll
            for (int e = 0; e < 4; ++e) {
                b_hi[e] = bf16s(k0[e]);     b_lo[e] = bf16s(k0[e] - sbf16(b_hi[e]));
                b_hi[4 + e] = bf16s(k1[e]); b_lo[4 + e] = bf16s(k1[e] - sbf16(b_hi[4 + e]));
            }
            acc[mj] = __builtin_amdgcn_mfma_f32_16x16x32_bf16(a_hi, b_hi, acc[mj], 0, 0, 0);
            acc[mj] = __builtin_amdgcn_mfma_f32_16x16x32_bf16(a_lo, b_hi, acc[mj], 0, 0, 0);
            acc[mj] = __builtin_amdgcn_mfma_f32_16x16x32_bf16(a_hi, b_lo, acc[mj], 0, 0, 0);
        }
    }
#pragma unroll
    for (int mj = 0; mj < 4; ++mj)
#pragma unroll
        for (int r = 0; r < 4; ++r) {
            int c = cw + 4 * g + r;
            int m = mj * 16 + l16;
            KVTb[((size_t)b * CC + c) * DD + m] =
                __float2bfloat16(acc[mj][r] + bv[c] * Ksum[b * DD + m]);
        }
}

// ---- out[c][n] = x + (gamma/dot(Q[n],Ksum+eps)) * sum_m KVT[c][m]*Q[n][m]
//      MFMA K=64, norm fused in-register ----
__global__ __launch_bounds__(256) void k_out(const float* __restrict__ x,
                                             const __hip_bfloat16* __restrict__ Qb,
                                             const __hip_bfloat16* __restrict__ KVTb,
                                             const float* __restrict__ Ksum,
                                             const float* __restrict__ gamma,
                                             float* __restrict__ out) {
    int b = blockIdx.z;
    int c_blk = blockIdx.x * 128, n_blk = blockIdx.y * 128;
    int wave = threadIdx.x >> 6, lane = threadIdx.x & 63;
    int cw = c_blk + (wave >> 1) * 64, nw = n_blk + (wave & 1) * 64;
    int l16 = lane & 15, g = lane >> 4;

    float ksv[2][8];
#pragma unroll
    for (int ck = 0; ck < 2; ++ck)
#pragma unroll
        for (int e = 0; e < 8; ++e)
            ksv[ck][e] = Ksum[b * DD + (ck * 4 + g) * 8 + e] + EPSV;

    f32x4 acc[4][4] = {};
    float dot[4] = {0.f, 0.f, 0.f, 0.f};
    const short8* ap = reinterpret_cast<const short8*>(KVTb) + ((size_t)b * CC + cw) * 8;
    const short8* bp = reinterpret_cast<const short8*>(Qb) + ((size_t)b * NN + nw) * 8;
#pragma unroll
    for (int ck = 0; ck < 2; ++ck) {
        int ch = ck * 4 + g;
        short8 af[4], bf[4];
#pragma unroll
        for (int i = 0; i < 4; ++i) af[i] = ap[(size_t)(i * 16 + l16) * 8 + ch];
#pragma unroll
        for (int i = 0; i < 4; ++i) bf[i] = bp[(size_t)(i * 16 + l16) * 8 + ch];
#pragma unroll
        for (int j = 0; j < 4; ++j)
#pragma unroll
            for (int e = 0; e < 8; ++e)
                dot[j] = fmaf(sbf16(bf[j][e]), ksv[ck][e], dot[j]);
#pragma unroll
        for (int i = 0; i < 4; ++i)
#pragma unroll
            for (int j = 0; j < 4; ++j)
                acc[i][j] = __builtin_amdgcn_mfma_f32_16x16x32_bf16(af[i], bf[j], acc[i][j], 0, 0, 0);
    }
    float gm = gamma[0];
    float sc[4];
#pragma unroll
    for (int j = 0; j < 4; ++j) {
        float d = dot[j];
        d += __shfl_xor(d, 16, 64);
        d += __shfl_xor(d, 32, 64);
        sc[j] = gm / d;
    }
    const float* xb = x + (size_t)b * CC * NN;
    float* ob = out + (size_t)b * CC * NN;
#pragma unroll
    for (int i = 0; i < 4; ++i)
#pragma unroll
        for (int r = 0; r < 4; ++r) {
            int c = cw + i * 16 + 4 * g + r;
            size_t rowoff = (size_t)c * NN;
#pragma unroll
            for (int j = 0; j < 4; ++j) {
                int n = nw + j * 16 + l16;
                ob[rowoff + n] = xb[rowoff + n] + sc[j] * acc[i][j][r];
            }
        }
}

extern "C" void kernel_launch(void* const* d_in, const int* in_sizes, int n_in,
                              void* d_out, int out_size, void* d_ws, size_t ws_size,
                              hipStream_t stream) {
    const float* x     = (const float*)d_in[0];
    const float* Wq    = (const float*)d_in[1];
    const float* bq    = (const float*)d_in[2];
    const float* Wk    = (const float*)d_in[3];
    const float* bk    = (const float*)d_in[4];
    const float* Wv    = (const float*)d_in[5];
    const float* bv    = (const float*)d_in[6];
    const float* gamma = (const float*)d_in[7];
    float* out = (float*)d_out;

    float* ws    = (float*)d_ws;
    float* KX    = ws;                                   // B*D*C fp32 (2MB)
    float* Ksum  = KX + (size_t)BB * DD * CC;            // B*D fp32
    __hip_bfloat16* Qb   = (__hip_bfloat16*)(Ksum + BB * DD);  // B*N*D bf16
    __hip_bfloat16* Kb   = Qb + (size_t)BB * NN * DD;    // B*D*N bf16
    __hip_bfloat16* KVTb = Kb + (size_t)BB * DD * NN;    // B*C*D bf16
    __hip_bfloat16* Wcat = KVTb + (size_t)BB * CC * DD;  // 128*C bf16

    k_prep<<<dim3(769), dim3(256), 0, stream>>>(Wq, Wk, Wcat, KX, Ksum);
    k_proj<<<dim3(NN / 128, BB), dim3(256), 0, stream>>>(x, Wcat, bq, bk, Qb, Kb, Ksum);
    k_kx<<<dim3(2, 16, BB), dim3(256), 0, stream>>>(Kb, x, KX);
    k_kv<<<dim3(CC / 64, BB), dim3(256), 0, stream>>>(KX, Wv, bv, Ksum, KVTb);
    k_out<<<dim3(CC / 128, NN / 128, BB), dim3(256), 0, stream>>>(x, Qb, KVTb, Ksum, gamma, out);
}

// Round 7
// 198.114 us; speedup vs baseline: 4.5634x; 1.0839x over previous
//
#include <hip/hip_runtime.h>
#include <hip/hip_bf16.h>
#include <math.h>

#define BB 16
#define CC 512
#define DD 64
#define NN 4096
#define EPSV 1e-6f

typedef __attribute__((ext_vector_type(8))) short short8;
typedef __attribute__((ext_vector_type(4))) short s16x4;
typedef __attribute__((ext_vector_type(4))) float f32x4;

__device__ __forceinline__ float softplus_f(float v) {
    return fmaxf(v, 0.0f) + log1pf(expf(-fabsf(v)));
}
__device__ __forceinline__ short bf16s(float f) {
    __hip_bfloat16 h = __float2bfloat16(f);
    return __builtin_bit_cast(short, h);
}
__device__ __forceinline__ float sbf16(short s) {
    return __bfloat162float(__builtin_bit_cast(__hip_bfloat16, s));
}

// ---- prep: Wcat bf16 [128][512] (blocks 0-255), zero KX (256-767), zero Ksum (768) ----
__global__ __launch_bounds__(256) void k_prep(const float* __restrict__ Wq,
                                              const float* __restrict__ Wk,
                                              __hip_bfloat16* __restrict__ Wcat,
                                              float* __restrict__ KX,
                                              float* __restrict__ Ksum) {
    int blk = blockIdx.x;
    if (blk < 256) {
        int i = blk * 256 + threadIdx.x;
        int j = i >> 9, c = i & 511;
        float v = (j < DD) ? Wq[j * CC + c] : Wk[(j - DD) * CC + c];
        Wcat[i] = __float2bfloat16(v);
    } else if (blk < 768) {
        int i = (blk - 256) * 256 + threadIdx.x;   // 512*256 f32x4 = 2MB
        f32x4 z = {0.f, 0.f, 0.f, 0.f};
        reinterpret_cast<f32x4*>(KX)[i] = z;
    } else {
        f32x4 z = {0.f, 0.f, 0.f, 0.f};
        reinterpret_cast<f32x4*>(Ksum)[threadIdx.x] = z;  // 1024 floats
    }
}

// ---- Q/K projection via MFMA, x staged through LDS (fused transpose, double-buffered).
//      Also accumulates Ksum[b][m]. Qb[b][n][d] bf16 ; Kb[b][m][n] bf16 ----
__global__ __launch_bounds__(256) void k_proj(const float* __restrict__ x,
                                              const __hip_bfloat16* __restrict__ Wcat,
                                              const float* __restrict__ bq,
                                              const float* __restrict__ bk,
                                              __hip_bfloat16* __restrict__ Qb,
                                              __hip_bfloat16* __restrict__ Kb,
                                              float* __restrict__ Ksum) {
    // xs: 32-c chunk of x, bf16, [c][n] rows padded to 132 u16 (264 B)
    // ws: 32-c chunk of Wcat, bf16, [j][c] rows padded to 40 u16 (80 B)
    __shared__ unsigned short xs[2][32][132];
    __shared__ unsigned short ws[2][128][40];

    int b = blockIdx.y;
    int n_blk = blockIdx.x * 128;
    int t = threadIdx.x;
    int wave = t >> 6, lane = t & 63;
    int nwl = wave * 32;                    // wave's local n base
    int n_wave = n_blk + nwl;
    int l16 = lane & 15, g = lane >> 4;

    // staging assignments
    int sv = t & 31;                        // x: 4-float group along n
    int sc = t >> 5;                        // x: base c-row (0..7), rows sc+8i
    int wj = t >> 1;                        // W: row j (0..127)
    int wh = t & 1;                         // W: 16-elem half of the 32-c chunk

    const float* xb = x + (size_t)b * CC * NN + n_blk + sv * 4;
    const unsigned short* wg = reinterpret_cast<const unsigned short*>(Wcat)
                               + (size_t)wj * 512 + wh * 16;

    f32x4 xr[4];
    s16x4 wr[4];

    auto loadx = [&](int c0) {
#pragma unroll
        for (int i = 0; i < 4; ++i)
            xr[i] = *reinterpret_cast<const f32x4*>(xb + (size_t)(c0 + sc + i * 8) * NN);
    };
    auto loadw = [&](int c0) {
#pragma unroll
        for (int k = 0; k < 4; ++k)
            wr[k] = *reinterpret_cast<const s16x4*>(wg + c0 + k * 4);
    };
    auto writex = [&](int bi) {
#pragma unroll
        for (int i = 0; i < 4; ++i) {
            s16x4 pv;
#pragma unroll
            for (int j = 0; j < 4; ++j) pv[j] = bf16s(xr[i][j]);
            *reinterpret_cast<s16x4*>(&xs[bi][sc + i * 8][sv * 4]) = pv;
        }
    };
    auto writew = [&](int bi) {
#pragma unroll
        for (int k = 0; k < 4; ++k)
            *reinterpret_cast<s16x4*>(&ws[bi][wj][wh * 16 + k * 4]) = wr[k];
    };

    f32x4 accQ[2][4] = {};                  // Q: D[n][j]
    f32x4 accK[4][2] = {};                  // K: D[j][n]

    loadx(0); loadw(0);
    writex(0); writew(0);

    for (int ck = 0; ck < 16; ++ck) {
        int cur = ck & 1;
        if (ck < 15) { loadx((ck + 1) * 32); loadw((ck + 1) * 32); }  // issue early (T14)
        __syncthreads();                     // buf[cur] ready; prev reads of buf[cur^1] done
        short8 xf[2], wf[8];
#pragma unroll
        for (int nf = 0; nf < 2; ++nf) {
            short8 v;
#pragma unroll
            for (int e = 0; e < 8; ++e)
                v[e] = (short)xs[cur][g * 8 + e][nwl + nf * 16 + l16];
            xf[nf] = v;
        }
#pragma unroll
        for (int jf = 0; jf < 8; ++jf)
            wf[jf] = *reinterpret_cast<const short8*>(&ws[cur][jf * 16 + l16][g * 8]);
#pragma unroll
        for (int nf = 0; nf < 2; ++nf)
#pragma unroll
            for (int jf = 0; jf < 4; ++jf)
                accQ[nf][jf] = __builtin_amdgcn_mfma_f32_16x16x32_bf16(xf[nf], wf[jf], accQ[nf][jf], 0, 0, 0);
#pragma unroll
        for (int jf = 0; jf < 4; ++jf)
#pragma unroll
            for (int nf = 0; nf < 2; ++nf)
                accK[jf][nf] = __builtin_amdgcn_mfma_f32_16x16x32_bf16(wf[4 + jf], xf[nf], accK[jf][nf], 0, 0, 0);
        if (ck < 15) { writex(cur ^ 1); writew(cur ^ 1); }   // other buffer: no race with cur readers
    }

    // Q epilogue: row n = n_wave + nf*16 + 4g + r, col j = jf*16 + l16
#pragma unroll
    for (int nf = 0; nf < 2; ++nf)
#pragma unroll
        for (int jf = 0; jf < 4; ++jf)
#pragma unroll
            for (int r = 0; r < 4; ++r) {
                int n = n_wave + nf * 16 + 4 * g + r;
                int j = jf * 16 + l16;
                float v = softplus_f(accQ[nf][jf][r] + bq[j]);
                Qb[((size_t)b * NN + n) * DD + j] = __float2bfloat16(v);
            }
    // K epilogue: row m = jf*16 + 4g + r, col n = n_wave + nf*16 + l16; fused Ksum
#pragma unroll
    for (int jf = 0; jf < 4; ++jf)
#pragma unroll
        for (int r = 0; r < 4; ++r) {
            int m = jf * 16 + 4 * g + r;
            float s = 0.f;
#pragma unroll
            for (int nf = 0; nf < 2; ++nf) {
                int n = n_wave + nf * 16 + l16;
                float v = softplus_f(accK[jf][nf][r] + bk[m]);
                Kb[((size_t)b * DD + m) * NN + n] = __float2bfloat16(v);
                s += v;
            }
            s += __shfl_xor(s, 1, 64);
            s += __shfl_xor(s, 2, 64);
            s += __shfl_xor(s, 4, 64);
            s += __shfl_xor(s, 8, 64);
            if (l16 == 0) atomicAdd(&Ksum[b * DD + m], s);
        }
}

// ---- KX[b][m][c] += sum_nn Kb[m][nn]*x[c][nn]  (MFMA, no LDS, split-K atomics) ----
__global__ __launch_bounds__(256) void k_kx(const __hip_bfloat16* __restrict__ Kb,
                                            const float* __restrict__ x,
                                            float* __restrict__ KX) {
    int b = blockIdx.z;
    int n0 = blockIdx.y * 256;                // 16 n-chunks
    int c0 = blockIdx.x * 256;                // 2 c-halves
    int wave = threadIdx.x >> 6, lane = threadIdx.x & 63;
    int cw = c0 + wave * 64;                  // wave owns 64 c-cols
    int l16 = lane & 15, g = lane >> 4;

    f32x4 acc[4][4] = {};                     // [mi][cj]
    const __hip_bfloat16* kp = Kb + (size_t)b * DD * NN;
    const float* xp = x + (size_t)b * CC * NN;

#pragma unroll
    for (int ks = 0; ks < 8; ++ks) {          // 256 n in steps of 32
        int nk = n0 + ks * 32 + g * 8;
        short8 af[4];
#pragma unroll
        for (int mi = 0; mi < 4; ++mi)
            af[mi] = *reinterpret_cast<const short8*>(kp + (size_t)(mi * 16 + l16) * NN + nk);
        short8 bf[4];
#pragma unroll
        for (int cj = 0; cj < 4; ++cj) {
            const float* xr = xp + (size_t)(cw + cj * 16 + l16) * NN + nk;
            f32x4 lo = *reinterpret_cast<const f32x4*>(xr);
            f32x4 hi = *reinterpret_cast<const f32x4*>(xr + 4);
            short8 v;
#pragma unroll
            for (int e = 0; e < 4; ++e) { v[e] = bf16s(lo[e]); v[4 + e] = bf16s(hi[e]); }
            bf[cj] = v;
        }
#pragma unroll
        for (int mi = 0; mi < 4; ++mi)
#pragma unroll
            for (int cj = 0; cj < 4; ++cj)
                acc[mi][cj] = __builtin_amdgcn_mfma_f32_16x16x32_bf16(af[mi], bf[cj], acc[mi][cj], 0, 0, 0);
    }
#pragma unroll
    for (int mi = 0; mi < 4; ++mi)
#pragma unroll
        for (int cj = 0; cj < 4; ++cj)
#pragma unroll
            for (int r = 0; r < 4; ++r) {
                int m = mi * 16 + 4 * g + r;
                int c = cw + cj * 16 + l16;
                atomicAdd(&KX[((size_t)(b * DD + m)) * CC + c], acc[mi][cj][r]);
            }
}

// ---- KVTb[b][c][m] = sum_cp KX[b][m][cp]*Wv[c][cp] + bv[c]*Ksum[b][m]
//      MFMA, no LDS, split hi/lo bf16 for ~fp32 accuracy. ----
__global__ __launch_bounds__(256) void k_kv(const float* __restrict__ KX,
                                            const float* __restrict__ Wv,
                                            const float* __restrict__ bv,
                                            const float* __restrict__ Ksum,
                                            __hip_bfloat16* __restrict__ KVTb) {
    int b = blockIdx.y;
    int c0 = blockIdx.x * 64;
    int wave = threadIdx.x >> 6, lane = threadIdx.x & 63;
    int cw = c0 + wave * 16;                  // wave owns 16 c-rows, all 64 m
    int l16 = lane & 15, g = lane >> 4;

    f32x4 acc[4] = {};                        // [mj]
    const float* wvp = Wv + (size_t)(cw + l16) * CC;
    const float* kxp = KX + (size_t)b * DD * CC;

#pragma unroll
    for (int ck = 0; ck < 16; ++ck) {         // 512 cp in steps of 32
        int cp = ck * 32 + g * 8;
        f32x4 w0 = *reinterpret_cast<const f32x4*>(wvp + cp);
        f32x4 w1 = *reinterpret_cast<const f32x4*>(wvp + cp + 4);
        short8 a_hi, a_lo;
#pragma unroll
        for (int e = 0; e < 4; ++e) {
            a_hi[e] = bf16s(w0[e]);     a_lo[e] = bf16s(w0[e] - sbf16(a_hi[e]));
            a_hi[4 + e] = bf16s(w1[e]); a_lo[4 + e] = bf16s(w1[e] - sbf16(a_hi[4 + e]));
        }
#pragma unroll
        for (int mj = 0; mj < 4; ++mj) {
            const float* kr = kxp + (size_t)(mj * 16 + l16) * CC + cp;
            f32x4 k0 = *reinterpret_cast<const f32x4*>(kr);
            f32x4 k1 = *reinterpret_cast<const f32x4*>(kr + 4);
            short8 b_hi, b_lo;
#pragma unroll
            for (int e = 0; e < 4; ++e) {
                b_hi[e] = bf16s(k0[e]);     b_lo[e] = bf16s(k0[e] - sbf16(b_hi[e]));
                b_hi[4 + e] = bf16s(k1[e]); b_lo[4 + e] = bf16s(k1[e] - sbf16(b_hi[4 + e]));
            }
            acc[mj] = __builtin_amdgcn_mfma_f32_16x16x32_bf16(a_hi, b_hi, acc[mj], 0, 0, 0);
            acc[mj] = __builtin_amdgcn_mfma_f32_16x16x32_bf16(a_lo, b_hi, acc[mj], 0, 0, 0);
            acc[mj] = __builtin_amdgcn_mfma_f32_16x16x32_bf16(a_hi, b_lo, acc[mj], 0, 0, 0);
        }
    }
#pragma unroll
    for (int mj = 0; mj < 4; ++mj)
#pragma unroll
        for (int r = 0; r < 4; ++r) {
            int c = cw + 4 * g + r;
            int m = mj * 16 + l16;
            KVTb[((size_t)b * CC + c) * DD + m] =
                __float2bfloat16(acc[mj][r] + bv[c] * Ksum[b * DD + m]);
        }
}

// ---- out[c][n] = x + (gamma/dot(Q[n],Ksum+eps)) * sum_m KVT[c][m]*Q[n][m]
//      MFMA K=64, norm fused in-register ----
__global__ __launch_bounds__(256) void k_out(const float* __restrict__ x,
                                             const __hip_bfloat16* __restrict__ Qb,
                                             const __hip_bfloat16* __restrict__ KVTb,
                                             const float* __restrict__ Ksum,
                                             const float* __restrict__ gamma,
                                             float* __restrict__ out) {
    int b = blockIdx.z;
    int c_blk = blockIdx.x * 128, n_blk = blockIdx.y * 128;
    int wave = threadIdx.x >> 6, lane = threadIdx.x & 63;
    int cw = c_blk + (wave >> 1) * 64, nw = n_blk + (wave & 1) * 64;
    int l16 = lane & 15, g = lane >> 4;

    float ksv[2][8];
#pragma unroll
    for (int ck = 0; ck < 2; ++ck)
#pragma unroll
        for (int e = 0; e < 8; ++e)
            ksv[ck][e] = Ksum[b * DD + (ck * 4 + g) * 8 + e] + EPSV;

    f32x4 acc[4][4] = {};
    float dot[4] = {0.f, 0.f, 0.f, 0.f};
    const short8* ap = reinterpret_cast<const short8*>(KVTb) + ((size_t)b * CC + cw) * 8;
    const short8* bp = reinterpret_cast<const short8*>(Qb) + ((size_t)b * NN + nw) * 8;
#pragma unroll
    for (int ck = 0; ck < 2; ++ck) {
        int ch = ck * 4 + g;
        short8 af[4], bf[4];
#pragma unroll
        for (int i = 0; i < 4; ++i) af[i] = ap[(size_t)(i * 16 + l16) * 8 + ch];
#pragma unroll
        for (int i = 0; i < 4; ++i) bf[i] = bp[(size_t)(i * 16 + l16) * 8 + ch];
#pragma unroll
        for (int j = 0; j < 4; ++j)
#pragma unroll
            for (int e = 0; e < 8; ++e)
                dot[j] = fmaf(sbf16(bf[j][e]), ksv[ck][e], dot[j]);
#pragma unroll
        for (int i = 0; i < 4; ++i)
#pragma unroll
            for (int j = 0; j < 4; ++j)
                acc[i][j] = __builtin_amdgcn_mfma_f32_16x16x32_bf16(af[i], bf[j], acc[i][j], 0, 0, 0);
    }
    float gm = gamma[0];
    float sc[4];
#pragma unroll
    for (int j = 0; j < 4; ++j) {
        float d = dot[j];
        d += __shfl_xor(d, 16, 64);
        d += __shfl_xor(d, 32, 64);
        sc[j] = gm / d;
    }
    const float* xb = x + (size_t)b * CC * NN;
    float* ob = out + (size_t)b * CC * NN;
#pragma unroll
    for (int i = 0; i < 4; ++i)
#pragma unroll
        for (int r = 0; r < 4; ++r) {
            int c = cw + i * 16 + 4 * g + r;
            size_t rowoff = (size_t)c * NN;
#pragma unroll
            for (int j = 0; j < 4; ++j) {
                int n = nw + j * 16 + l16;
                ob[rowoff + n] = xb[rowoff + n] + sc[j] * acc[i][j][r];
            }
        }
}

extern "C" void kernel_launch(void* const* d_in, const int* in_sizes, int n_in,
                              void* d_out, int out_size, void* d_ws, size_t ws_size,
                              hipStream_t stream) {
    const float* x     = (const float*)d_in[0];
    const float* Wq    = (const float*)d_in[1];
    const float* bq    = (const float*)d_in[2];
    const float* Wk    = (const float*)d_in[3];
    const float* bk    = (const float*)d_in[4];
    const float* Wv    = (const float*)d_in[5];
    const float* bv    = (const float*)d_in[6];
    const float* gamma = (const float*)d_in[7];
    float* out = (float*)d_out;

    float* ws    = (float*)d_ws;
    float* KX    = ws;                                   // B*D*C fp32 (2MB)
    float* Ksum  = KX + (size_t)BB * DD * CC;            // B*D fp32
    __hip_bfloat16* Qb   = (__hip_bfloat16*)(Ksum + BB * DD);  // B*N*D bf16
    __hip_bfloat16* Kb   = Qb + (size_t)BB * NN * DD;    // B*D*N bf16
    __hip_bfloat16* KVTb = Kb + (size_t)BB * DD * NN;    // B*C*D bf16
    __hip_bfloat16* Wcat = KVTb + (size_t)BB * CC * DD;  // 128*C bf16

    k_prep<<<dim3(769), dim3(256), 0, stream>>>(Wq, Wk, Wcat, KX, Ksum);
    k_proj<<<dim3(NN / 128, BB), dim3(256), 0, stream>>>(x, Wcat, bq, bk, Qb, Kb, Ksum);
    k_kx<<<dim3(2, 16, BB), dim3(256), 0, stream>>>(Kb, x, KX);
    k_kv<<<dim3(CC / 64, BB), dim3(256), 0, stream>>>(KX, Wv, bv, Ksum, KVTb);
    k_out<<<dim3(CC / 128, NN / 128, BB), dim3(256), 0, stream>>>(x, Qb, KVTb, Ksum, gamma, out);
}